// Round 17
// baseline (400.648 us; speedup 1.0000x reference)
//
#include <hip/hip_runtime.h>
#include <hip/hip_fp16.h>

#define N_NODES 100000
#define N_EDGES 1600000
#define EP (N_EDGES + N_NODES)
#define NG 64
#define NH 4
#define POOL_NPB 256
#define BSHIFT 7
#define BNODES 128
#define NBUCK 782    // cdiv(N_NODES, 128)
#define BCAP 3072    // per-bucket capacity (mean 2176)
#define BCHUNK 16384 // edges per k_bucket block (two-pass)
#define NBLK2 (N_NODES / 16)
#define NBLK1 (N_NODES / 32)
#define NBINS 64

static inline int cdiv(int a, int b) { return (a + b - 1) / b; }

typedef _Float16 half8 __attribute__((ext_vector_type(8)));
typedef float f32x4 __attribute__((ext_vector_type(4)));

__device__ __forceinline__ float lrelu(float x) { return x >= 0.f ? x : 0.2f * x; }

// ---------------- CSR build: two-pass bucket sort (long runs -> coalesced writes) ----------------
__global__ __launch_bounds__(256) void k_bucket(const int* __restrict__ ei,
                                                int* __restrict__ gCursor,
                                                unsigned int* __restrict__ pairs) {
  __shared__ int cnt[NBUCK];
  __shared__ int base[NBUCK];
  int tid = threadIdx.x;
  for (int b = tid; b < NBUCK; b += 256) cnt[b] = 0;
  __syncthreads();
  int e0 = blockIdx.x * BCHUNK;
  int eEnd = min(EP, e0 + BCHUNK);
  for (int e = e0 + tid; e < eEnd; e += 256) {
    int d = (e < N_EDGES) ? ei[N_EDGES + e] : (e - N_EDGES);
    atomicAdd(&cnt[d >> BSHIFT], 1);
  }
  __syncthreads();
  for (int b = tid; b < NBUCK; b += 256) {
    int c = cnt[b];
    base[b] = c ? atomicAdd(&gCursor[b], c) : 0;
    cnt[b] = 0;  // reuse as cursor
  }
  __syncthreads();
  for (int e = e0 + tid; e < eEnd; e += 256) {
    int d, s;
    if (e < N_EDGES) {
      d = ei[N_EDGES + e];  // L2-warm from pass A
      s = ei[e];
    } else {
      d = s = e - N_EDGES;
    }
    int b = d >> BSHIFT;
    int r = atomicAdd(&cnt[b], 1);
    pairs[base[b] + r] = ((unsigned int)s << BSHIFT) | (unsigned int)(d & (BNODES - 1));
  }
}

__global__ __launch_bounds__(1024) void k_bscan(const int* __restrict__ gCursor,
                                                int* __restrict__ bstart) {
  __shared__ int sh[1024];
  int t = threadIdx.x;
  int v = (t < NBUCK) ? (gCursor[t] - t * BCAP) : 0;
  sh[t] = v;
  __syncthreads();
  for (int off = 1; off < 1024; off <<= 1) {
    int add = (t >= off) ? sh[t - off] : 0;
    __syncthreads();
    sh[t] += add;
    __syncthreads();
  }
  if (t < NBUCK) {
    bstart[t] = sh[t] - v;
    if (t == NBUCK - 1) bstart[NBUCK] = sh[t];
  }
}

// per-bucket counting sort in LDS + degree histogram
__global__ __launch_bounds__(256) void k_build(const unsigned int* __restrict__ pairs,
                                               const int* __restrict__ bstart,
                                               int* __restrict__ indptr, int* __restrict__ esrc,
                                               int* __restrict__ ghist) {
  __shared__ int cnt[BNODES];
  __shared__ int exc[BNODES];
  __shared__ int ptr[BNODES];
  __shared__ int dh[NBINS];
  __shared__ int eLds[BCAP];
  int b = blockIdx.x;
  int tid = threadIdx.x;
  int obase = bstart[b];
  int nE = bstart[b + 1] - obase;
  int pbase = b * BCAP;
  if (tid < BNODES) cnt[tid] = 0;
  if (tid >= BNODES && tid < BNODES + NBINS) dh[tid - BNODES] = 0;
  __syncthreads();
  unsigned int stV[12];
#pragma unroll
  for (int i = 0; i < 12; i++) {
    int idx = i * 256 + tid;
    stV[i] = 0xFFFFFFFFu;
    if (idx < nE) {
      unsigned int v = pairs[pbase + idx];
      stV[i] = v;
      atomicAdd(&cnt[v & (BNODES - 1)], 1);
    }
  }
  __syncthreads();
  if (tid < BNODES) ptr[tid] = cnt[tid];
  __syncthreads();
  for (int off = 1; off < BNODES; off <<= 1) {
    int add = (tid < BNODES && tid >= off) ? ptr[tid - off] : 0;
    __syncthreads();
    if (tid < BNODES) ptr[tid] += add;
    __syncthreads();
  }
  if (tid < BNODES) {
    exc[tid] = ptr[tid] - cnt[tid];
    int n = (b << BSHIFT) + tid;
    if (n < N_NODES) {
      indptr[n] = obase + exc[tid];
      atomicAdd(&dh[min(cnt[tid], NBINS - 1)], 1);
    }
    cnt[tid] = 0;  // reuse as cursor
  }
  if (b == NBUCK - 1 && tid == 0) indptr[N_NODES] = bstart[NBUCK];
  __syncthreads();
  if (tid < NBINS && dh[tid]) atomicAdd(&ghist[tid], dh[tid]);
#pragma unroll
  for (int i = 0; i < 12; i++) {
    if (stV[i] != 0xFFFFFFFFu) {
      int ln = stV[i] & (BNODES - 1);
      int r = atomicAdd(&cnt[ln], 1);
      eLds[exc[ln] + r] = (int)(stV[i] >> BSHIFT);
    }
  }
  __syncthreads();
  for (int idx = tid; idx < nE; idx += 256) esrc[obase + idx] = eLds[idx];
}

// ---------------- degree-sort perm + inverse ----------------
__global__ void k_dscan(const int* __restrict__ ghist, int* __restrict__ binCur) {
  if (threadIdx.x == 0) {
    int acc = 0;
    for (int b = 0; b < NBINS; b++) {
      binCur[b] = acc;
      acc += ghist[b];
    }
  }
}

__global__ __launch_bounds__(256) void k_dscat(const int* __restrict__ indptr,
                                               int* __restrict__ binCur,
                                               int* __restrict__ perm, int* __restrict__ pinv) {
  __shared__ int cnt[NBINS];
  __shared__ int base[NBINS];
  int t = threadIdx.x;
  if (t < NBINS) cnt[t] = 0;
  __syncthreads();
  int binr[2], nr[2];
#pragma unroll
  for (int i = 0; i < 2; i++) {
    int n = blockIdx.x * 512 + i * 256 + t;
    binr[i] = -1;
    if (n < N_NODES) {
      int deg = indptr[n + 1] - indptr[n];
      binr[i] = min(deg, NBINS - 1);
      nr[i] = n;
      atomicAdd(&cnt[binr[i]], 1);
    }
  }
  __syncthreads();
  if (t < NBINS) {
    base[t] = cnt[t] ? atomicAdd(&binCur[t], cnt[t]) : 0;
    cnt[t] = 0;
  }
  __syncthreads();
#pragma unroll
  for (int i = 0; i < 2; i++) {
    if (binr[i] >= 0) {
      int r = atomicAdd(&cnt[binr[i]], 1);
      int pos = base[binr[i]] + r;
      perm[pos] = nr[i];
      pinv[nr[i]] = pos;
    }
  }
}

// ---------------- translate edges to permuted space + per-permuted-node extents ----------------
__global__ __launch_bounds__(256) void k_etrans(const int* __restrict__ esrc,
                                                const int* __restrict__ pinv,
                                                const int* __restrict__ indptr,
                                                const int* __restrict__ perm,
                                                int* __restrict__ esrc2,
                                                int* __restrict__ stp, int* __restrict__ enp) {
  int i = blockIdx.x * 256 + threadIdx.x;
  if (i < EP) esrc2[i] = pinv[esrc[i]];
  if (i < N_NODES) {
    int n = perm[i];
    stp[i] = indptr[n];
    enp[i] = indptr[n + 1];
  }
}

// ---------------- prep: attention-fold vectors + MFMA B-fragment packing + cursor init ----------------
template <int FIN, int D>
__device__ void wvec_impl(const float* __restrict__ W, const float* __restrict__ aS,
                          const float* __restrict__ aD, float* __restrict__ wS,
                          float* __restrict__ wD, int t) {
  if (t >= 4 * FIN) return;
  int h = t / FIN, k = t % FIN;
  float ss = 0.f, dd = 0.f;
  for (int d = 0; d < D; d++) {
    float w = W[k * (4 * D) + h * D + d];
    ss = fmaf(w, aS[h * D + d], ss);
    dd = fmaf(w, aD[h * D + d], dd);
  }
  wS[h * FIN + k] = ss;
  wD[h * FIN + k] = dd;
}

template <int D>
__device__ void wcvt_frag(const float* __restrict__ W, __half* __restrict__ wf, int frag, int l) {
  constexpr int NCT = D / 16;
  int kt = frag / NCT, ct = frag % NCT;
  half8 v;
#pragma unroll
  for (int j = 0; j < 8; j++) {
    int kk = kt * 32 + (l >> 4) * 8 + j;
    int k = kk >> 2, h = kk & 3;
    v[j] = (_Float16)W[k * (4 * D) + h * D + ct * 16 + (l & 15)];
  }
  *(half8*)(wf + (size_t)frag * 512 + l * 8) = v;
}

__global__ __launch_bounds__(256) void k_prep(const float* W1, const float* aS1, const float* aD1,
                                              const float* W2, const float* aS2, const float* aD2,
                                              const float* W3, const float* aS3, const float* aD3,
                                              float* wS1, float* wD1, float* wS2, float* wD2,
                                              float* wS3, float* wD3,
                                              __half* wf1, __half* wf2, __half* wf3,
                                              int* gCursor) {
  int b = blockIdx.x, t = threadIdx.x;
  int f = t >> 6, l = t & 63;
  if (b == 0) wvec_impl<8, 64>(W1, aS1, aD1, wS1, wD1, t);
  else if (b == 1) wvec_impl<64, 64>(W2, aS2, aD2, wS2, wD2, t);
  else if (b == 2) wvec_impl<64, 32>(W3, aS3, aD3, wS3, wD3, t);
  else if (b == 3) wcvt_frag<64>(W1, wf1, f, l);
  else if (b < 12) wcvt_frag<64>(W2, wf2, (b - 4) * 4 + f, l);
  else if (b < 16) wcvt_frag<32>(W3, wf3, (b - 12) * 4 + f, l);
  else {
    int idx = (b - 16) * 256 + t;
    if (idx < NBUCK) gCursor[idx] = idx * BCAP;
  }
}

// ---------------- layer-1 prep: permute x + attention dots (permuted space) ----------------
__global__ void k_prex1(const float* __restrict__ x, const int* __restrict__ perm,
                        const float* __restrict__ wS, const float* __restrict__ wD,
                        float* __restrict__ xp, float4* __restrict__ as4,
                        float4* __restrict__ ad4) {
  int p = blockIdx.x * blockDim.x + threadIdx.x;
  if (p >= N_NODES) return;
  int n = perm[p];
  float4 s = {0, 0, 0, 0}, d = {0, 0, 0, 0};
  float xv[8];
#pragma unroll
  for (int k = 0; k < 8; k++) {
    xv[k] = x[(size_t)n * 8 + k];
    s.x = fmaf(xv[k], wS[k], s.x);
    s.y = fmaf(xv[k], wS[8 + k], s.y);
    s.z = fmaf(xv[k], wS[16 + k], s.z);
    s.w = fmaf(xv[k], wS[24 + k], s.w);
    d.x = fmaf(xv[k], wD[k], d.x);
    d.y = fmaf(xv[k], wD[8 + k], d.y);
    d.z = fmaf(xv[k], wD[16 + k], d.z);
    d.w = fmaf(xv[k], wD[24 + k], d.w);
  }
  float4* xpv = (float4*)(xp + (size_t)p * 8);
  xpv[0] = make_float4(xv[0], xv[1], xv[2], xv[3]);
  xpv[1] = make_float4(xv[4], xv[5], xv[6], xv[7]);
  as4[p] = s;
  ad4[p] = d;
}

// ---------------- attention dots from permuted fp16 t (BN on the fly, read-only) ----------------
__global__ __launch_bounds__(256) void k_dots(const __half* __restrict__ t16,
                                              const float* __restrict__ scale,
                                              const float* __restrict__ shift,
                                              const float* __restrict__ wS,
                                              const float* __restrict__ wD,
                                              float4* __restrict__ as4, float4* __restrict__ ad4) {
  int lane = threadIdx.x & 63;
  int p = blockIdx.x * 4 + (threadIdx.x >> 6);
  if (p >= N_NODES) return;
  float v = fmaf(__half2float(t16[(size_t)p * 64 + lane]), scale[lane], shift[lane]);
  float p0 = v * wS[lane], p1 = v * wS[64 + lane], p2 = v * wS[128 + lane], p3 = v * wS[192 + lane];
  float q0 = v * wD[lane], q1 = v * wD[64 + lane], q2 = v * wD[128 + lane], q3 = v * wD[192 + lane];
#pragma unroll
  for (int off = 32; off; off >>= 1) {
    p0 += __shfl_xor(p0, off); p1 += __shfl_xor(p1, off);
    p2 += __shfl_xor(p2, off); p3 += __shfl_xor(p3, off);
    q0 += __shfl_xor(q0, off); q1 += __shfl_xor(q1, off);
    q2 += __shfl_xor(q2, off); q3 += __shfl_xor(q3, off);
  }
  if (lane == 0) {
    as4[p] = make_float4(p0, p1, p2, p3);
    ad4[p] = make_float4(q0, q1, q2, q3);
  }
}

// ---------------- fused layer-1: gather (8-lane groups, permuted space) + MFMA + BN partials ----------------
__global__ __launch_bounds__(256) void k_aggp1(const int* __restrict__ stp,
                                               const int* __restrict__ enp,
                                               const int* __restrict__ esrc2,
                                               const float* __restrict__ xp,
                                               const float4* __restrict__ as4,
                                               const float4* __restrict__ ad4,
                                               const __half* __restrict__ wfrag,
                                               const float* __restrict__ bias,
                                               __half* __restrict__ out16,
                                               float* __restrict__ part) {
  constexpr int GL = 8, NPW = 8, WB = NPW * (GL + 1);
  __shared__ int sOff[4 * WB];
  __shared__ float4 sW[4 * WB];
  __shared__ __align__(16) __half aT[32 * 40];
  int tid = threadIdx.x;
  int lane = tid & 63;
  int wv = tid >> 6;
  int q = lane & 7;
  int g = lane >> 3;
  int row = wv * 8 + g;
  int p = blockIdx.x * 32 + row;
  int e0 = stp[p], e1 = enp[p];
  float4 ad = ad4[p];
  int lbase = wv * WB + g * (GL + 1);
  const char* xb = (const char*)xp + q * 4;
  float s0 = 0.f, s1 = 0.f, s2 = 0.f, s3 = 0.f;
  float a0 = 0.f, a1 = 0.f, a2 = 0.f, a3 = 0.f;
  for (int c = e0; c < e1; c += GL) {
    int nc = min(GL, e1 - c);
    float w0 = 0.f, w1 = 0.f, w2 = 0.f, w3 = 0.f;
    int sB = 0;
    if (q < nc) {
      int sidx = esrc2[c + q];
      float4 av = as4[sidx];
      w0 = __expf(lrelu(av.x + ad.x));
      w1 = __expf(lrelu(av.y + ad.y));
      w2 = __expf(lrelu(av.z + ad.z));
      w3 = __expf(lrelu(av.w + ad.w));
      sB = sidx << 5;
    }
    s0 += w0; s1 += w1; s2 += w2; s3 += w3;
    sOff[lbase + q] = sB;
    sW[lbase + q] = make_float4(w0, w1, w2, w3);
    __builtin_amdgcn_wave_barrier();
    for (int i = 0; i < nc; ++i) {
      float4 w = sW[lbase + i];
      float xv = *(const float*)(xb + sOff[lbase + i]);
      a0 = fmaf(w.x, xv, a0);
      a1 = fmaf(w.y, xv, a1);
      a2 = fmaf(w.z, xv, a2);
      a3 = fmaf(w.w, xv, a3);
    }
    __builtin_amdgcn_wave_barrier();
  }
#pragma unroll
  for (int off = 1; off < GL; off <<= 1) {
    s0 += __shfl_xor(s0, off);
    s1 += __shfl_xor(s1, off);
    s2 += __shfl_xor(s2, off);
    s3 += __shfl_xor(s3, off);
  }
  float r0 = 1.f / (s0 + 1e-16f), r1 = 1.f / (s1 + 1e-16f);
  float r2 = 1.f / (s2 + 1e-16f), r3 = 1.f / (s3 + 1e-16f);
  __half2 p01 = __floats2half2_rn(a0 * r0, a1 * r1);
  __half2 p23 = __floats2half2_rn(a2 * r2, a3 * r3);
  uint2 pk = make_uint2(*(unsigned*)&p01, *(unsigned*)&p23);
  *(uint2*)&aT[row * 40 + q * 4] = pk;
  __syncthreads();
  int ct = wv;  // NCT = 4
  int m = lane & 15, kg = lane >> 4;
  half8 bv = *(const half8*)(wfrag + ((size_t)ct * 64 + lane) * 8);
  float bvs = bias[ct * 16 + m];
  float psum = 0.f, psq = 0.f;
#pragma unroll
  for (int tt = 0; tt < 2; tt++) {
    half8 avf = *(const half8*)&aT[(tt * 16 + m) * 40 + kg * 8];
    f32x4 cacc = (f32x4){0.f, 0.f, 0.f, 0.f};
    cacc = __builtin_amdgcn_mfma_f32_16x16x32_f16(avf, bv, cacc, 0, 0, 0);
#pragma unroll
    for (int j = 0; j < 4; j++) {
      int pr = blockIdx.x * 32 + tt * 16 + kg * 4 + j;
      float ov = fmaxf(fmaf(cacc[j], 0.25f, bvs), 0.f);
      out16[(size_t)pr * 64 + ct * 16 + m] = __float2half(ov);  // coalesced (permuted layout)
      psum += ov;
      psq = fmaf(ov, ov, psq);
    }
  }
  psum += __shfl_xor(psum, 16); psum += __shfl_xor(psum, 32);
  psq += __shfl_xor(psq, 16); psq += __shfl_xor(psq, 32);
  if (kg == 0) {
    part[(size_t)blockIdx.x * 128 + ct * 16 + m] = psum;
    part[(size_t)blockIdx.x * 128 + 64 + ct * 16 + m] = psq;
  }
}

// ---------------- fused gather + MFMA + BN partials (layers 2/3; permuted space) ----------------
template <int DOUT, bool OUTH>
__global__ __launch_bounds__(256) void k_aggp(const int* __restrict__ stp,
                                              const int* __restrict__ enp,
                                              const int* __restrict__ esrc2,
                                              const __half* __restrict__ xg,
                                              const float4* __restrict__ as4,
                                              const float4* __restrict__ ad4,
                                              const __half* __restrict__ wfrag,
                                              const float* __restrict__ bias,
                                              const float* __restrict__ scale,
                                              const float* __restrict__ shift,
                                              const int* __restrict__ perm,
                                              __half* __restrict__ out16,
                                              float* __restrict__ out32,
                                              float* __restrict__ part) {
  constexpr int NCT = DOUT / 16;
  constexpr int GL = 16, NPW = 4, WB = NPW * (GL + 1);
  __shared__ int sOff[4 * WB];
  __shared__ float4 sW[4 * WB];
  __shared__ __align__(16) __half aT[16 * 264];
  int tid = threadIdx.x;
  int lane = tid & 63;
  int wv = tid >> 6;
  int q = lane & 15;
  int g = lane >> 4;
  int row = wv * 4 + g;
  int p = blockIdx.x * 16 + row;
  int e0 = stp[p], e1 = enp[p];
  float4 ad = ad4[p];
  int lbase = wv * WB + g * (GL + 1);
  const char* xb = (const char*)xg + q * 8;
  float s0 = 0.f, s1 = 0.f, s2 = 0.f, s3 = 0.f;
  float a[4][4];
#pragma unroll
  for (int d = 0; d < 4; d++)
#pragma unroll
    for (int h = 0; h < 4; h++) a[d][h] = 0.f;

  for (int c = e0; c < e1; c += GL) {
    int nc = min(GL, e1 - c);
    float w0 = 0.f, w1 = 0.f, w2 = 0.f, w3 = 0.f;
    int sB = 0;
    if (q < nc) {
      int sidx = esrc2[c + q];
      float4 av = as4[sidx];
      w0 = __expf(lrelu(av.x + ad.x));
      w1 = __expf(lrelu(av.y + ad.y));
      w2 = __expf(lrelu(av.z + ad.z));
      w3 = __expf(lrelu(av.w + ad.w));
      sB = sidx << 7;
    }
    s0 += w0; s1 += w1; s2 += w2; s3 += w3;
    sOff[lbase + q] = sB;
    sW[lbase + q] = make_float4(w0, w1, w2, w3);
    __builtin_amdgcn_wave_barrier();
    for (int i = 0; i < nc; ++i) {
      float4 w = sW[lbase + i];
      uint2 px = *(const uint2*)(xb + sOff[lbase + i]);
      float2 f01 = __half22float2(*(const __half2*)&px.x);
      float2 f23 = __half22float2(*(const __half2*)&px.y);
      a[0][0] = fmaf(w.x, f01.x, a[0][0]); a[0][1] = fmaf(w.y, f01.x, a[0][1]);
      a[0][2] = fmaf(w.z, f01.x, a[0][2]); a[0][3] = fmaf(w.w, f01.x, a[0][3]);
      a[1][0] = fmaf(w.x, f01.y, a[1][0]); a[1][1] = fmaf(w.y, f01.y, a[1][1]);
      a[1][2] = fmaf(w.z, f01.y, a[1][2]); a[1][3] = fmaf(w.w, f01.y, a[1][3]);
      a[2][0] = fmaf(w.x, f23.x, a[2][0]); a[2][1] = fmaf(w.y, f23.x, a[2][1]);
      a[2][2] = fmaf(w.z, f23.x, a[2][2]); a[2][3] = fmaf(w.w, f23.x, a[2][3]);
      a[3][0] = fmaf(w.x, f23.y, a[3][0]); a[3][1] = fmaf(w.y, f23.y, a[3][1]);
      a[3][2] = fmaf(w.z, f23.y, a[3][2]); a[3][3] = fmaf(w.w, f23.y, a[3][3]);
    }
    __builtin_amdgcn_wave_barrier();
  }
#pragma unroll
  for (int off = 1; off < GL; off <<= 1) {
    s0 += __shfl_xor(s0, off);
    s1 += __shfl_xor(s1, off);
    s2 += __shfl_xor(s2, off);
    s3 += __shfl_xor(s3, off);
  }
  float r0 = 1.f / (s0 + 1e-16f), r1 = 1.f / (s1 + 1e-16f);
  float r2 = 1.f / (s2 + 1e-16f), r3 = 1.f / (s3 + 1e-16f);
  __half2 pp[8];
#pragma unroll
  for (int d = 0; d < 4; d++) {
    float sc = scale[q * 4 + d], sh = shift[q * 4 + d];
    pp[2 * d] = __floats2half2_rn(fmaf(a[d][0] * r0, sc, sh), fmaf(a[d][1] * r1, sc, sh));
    pp[2 * d + 1] = __floats2half2_rn(fmaf(a[d][2] * r2, sc, sh), fmaf(a[d][3] * r3, sc, sh));
  }
  uint4 lo = make_uint4(*(unsigned*)&pp[0], *(unsigned*)&pp[1], *(unsigned*)&pp[2], *(unsigned*)&pp[3]);
  uint4 hi = make_uint4(*(unsigned*)&pp[4], *(unsigned*)&pp[5], *(unsigned*)&pp[6], *(unsigned*)&pp[7]);
  *(uint4*)&aT[row * 264 + q * 16] = lo;
  *(uint4*)&aT[row * 264 + q * 16 + 8] = hi;
  __syncthreads();
  if (wv < NCT) {
    int ct = wv;
    int m = lane & 15, kg = lane >> 4;
    f32x4 cacc = (f32x4){0.f, 0.f, 0.f, 0.f};
#pragma unroll
    for (int kt = 0; kt < 8; kt++) {
      half8 avf = *(const half8*)&aT[m * 264 + kt * 32 + kg * 8];
      half8 bvf = *(const half8*)(wfrag + ((kt * NCT + ct) * 64 + lane) * 8);
      cacc = __builtin_amdgcn_mfma_f32_16x16x32_f16(avf, bvf, cacc, 0, 0, 0);
    }
    float bv = bias[ct * 16 + m];
    float psum = 0.f, psq = 0.f;
#pragma unroll
    for (int j = 0; j < 4; j++) {
      int pr = blockIdx.x * 16 + kg * 4 + j;
      float ov = fmaxf(fmaf(cacc[j], 0.25f, bv), 0.f);
      if constexpr (OUTH) {
        out16[(size_t)pr * DOUT + ct * 16 + m] = __float2half(ov);  // coalesced
      } else {
        int nr = perm[pr];  // back to original layout for pooling
        out32[(size_t)nr * DOUT + ct * 16 + m] = ov;
      }
      psum += ov;
      psq = fmaf(ov, ov, psq);
    }
    psum += __shfl_xor(psum, 16); psum += __shfl_xor(psum, 32);
    psq += __shfl_xor(psq, 16); psq += __shfl_xor(psq, 32);
    if (kg == 0) {
      part[(size_t)blockIdx.x * (2 * DOUT) + ct * 16 + m] = psum;
      part[(size_t)blockIdx.x * (2 * DOUT) + DOUT + ct * 16 + m] = psq;
    }
  }
}

// ---------------- BN finalize from per-block partials: grid = C blocks ----------------
template <int C>
__global__ __launch_bounds__(256) void k_bnfin2(const float* __restrict__ part, int nb,
                                                const float* __restrict__ g,
                                                const float* __restrict__ be,
                                                float* __restrict__ scale,
                                                float* __restrict__ shift) {
  int c = blockIdx.x;
  int t = threadIdx.x;
  float s = 0.f, q = 0.f;
  for (int b = t; b < nb; b += 256) {
    s += part[(size_t)b * (2 * C) + c];
    q += part[(size_t)b * (2 * C) + C + c];
  }
  __shared__ float sh[512];
  sh[t] = s;
  sh[256 + t] = q;
  __syncthreads();
  for (int step = 128; step; step >>= 1) {
    if (t < step) {
      sh[t] += sh[t + step];
      sh[256 + t] += sh[256 + t + step];
    }
    __syncthreads();
  }
  if (t == 0) {
    float mean = sh[0] / (float)N_NODES;
    float var = sh[256] / (float)N_NODES - mean * mean;
    float sc = g[c] * rsqrtf(var + 1e-5f);
    scale[c] = sc;
    shift[c] = be[c] - mean * sc;
  }
}

// ---------------- pooling (applies layer-3 BN on load; batch sorted, original layout) ----------------
__global__ __launch_bounds__(256) void k_pool(const float* __restrict__ f3,
                                              const int* __restrict__ batch,
                                              const float* __restrict__ scale,
                                              const float* __restrict__ shift,
                                              float* __restrict__ pool,
                                              float* __restrict__ cntg) {
  __shared__ float acc[NG][33];
  int t = threadIdx.x;
  for (int i = t; i < NG * 33; i += 256) ((float*)acc)[i] = 0.f;
  __syncthreads();
  int c = t & 31, rg = t >> 5;
  float sc = scale[c], sh = shift[c];
  int n0 = blockIdx.x * POOL_NPB;
  int n1 = min(N_NODES, n0 + POOL_NPB);
  float r = 0.f, rc = 0.f;
  int gcur = -1;
  for (int n = n0 + rg; n < n1; n += 8) {
    int g = batch[n];
    if (g != gcur) {
      if (gcur >= 0) {
        atomicAdd(&acc[gcur][c], r);
        if (c == 0) atomicAdd(&acc[gcur][32], rc);
      }
      gcur = g;
      r = 0.f;
      rc = 0.f;
    }
    r += fmaf(f3[(size_t)n * 32 + c], sc, sh);
    rc += 1.f;
  }
  if (gcur >= 0) {
    atomicAdd(&acc[gcur][c], r);
    if (c == 0) atomicAdd(&acc[gcur][32], rc);
  }
  __syncthreads();
  for (int i = t; i < NG * 32; i += 256) {
    int g = i >> 5, cc = i & 31;
    float v = acc[g][cc];
    if (v != 0.f) atomicAdd(&pool[i], v);
  }
  for (int g = t; g < NG; g += 256) {
    float v = acc[g][32];
    if (v != 0.f) atomicAdd(&cntg[g], v);
  }
}

__global__ void k_mlp(const float* __restrict__ pool, const float* __restrict__ cntg,
                      const float* __restrict__ Wp1, const float* __restrict__ bp1,
                      const float* __restrict__ Wp2, const float* __restrict__ bp2,
                      float* __restrict__ out) {
  int g = threadIdx.x;
  if (g >= NG) return;
  float inv = 1.f / fmaxf(cntg[g], 1.f);
  float p[32];
#pragma unroll
  for (int c = 0; c < 32; c++) p[c] = pool[g * 32 + c] * inv;
  float o = bp2[0];
  for (int j = 0; j < 16; j++) {
    float hsum = bp1[j];
#pragma unroll
    for (int c = 0; c < 32; c++) hsum = fmaf(p[c], Wp1[c * 16 + j], hsum);
    o = fmaf(fmaxf(hsum, 0.f), Wp2[j], o);
  }
  out[g] = o;
}

extern "C" void kernel_launch(void* const* d_in, const int* in_sizes, int n_in,
                              void* d_out, int out_size, void* d_ws, size_t ws_size,
                              hipStream_t stream) {
  const float* x = (const float*)d_in[0];
  const int* ei = (const int*)d_in[1];
  const int* batch = (const int*)d_in[2];
  const float* W1 = (const float*)d_in[3];
  const float* aS1 = (const float*)d_in[4];
  const float* aD1 = (const float*)d_in[5];
  const float* b1 = (const float*)d_in[6];
  const float* g1 = (const float*)d_in[7];
  const float* be1 = (const float*)d_in[8];
  const float* W2 = (const float*)d_in[9];
  const float* aS2 = (const float*)d_in[10];
  const float* aD2 = (const float*)d_in[11];
  const float* b2 = (const float*)d_in[12];
  const float* g2 = (const float*)d_in[13];
  const float* be2 = (const float*)d_in[14];
  const float* W3 = (const float*)d_in[15];
  const float* aS3 = (const float*)d_in[16];
  const float* aD3 = (const float*)d_in[17];
  const float* b3 = (const float*)d_in[18];
  const float* g3 = (const float*)d_in[19];
  const float* be3 = (const float*)d_in[20];
  const float* Wp1 = (const float*)d_in[21];
  const float* bp1 = (const float*)d_in[22];
  const float* Wp2 = (const float*)d_in[23];
  const float* bp2 = (const float*)d_in[24];
  float* out = (float*)d_out;

  size_t off = 0;
  auto alloc = [&](size_t bytes) -> void* {
    void* p = (char*)d_ws + off;
    off += (bytes + 255) & ~(size_t)255;
    return p;
  };
  // zeroed region (single memset): pool, cntg, ghist
  float* pool = (float*)alloc((size_t)NG * 32 * 4);
  float* cntg = (float*)alloc((size_t)NG * 4);
  int* ghist = (int*)alloc((size_t)NBINS * 4);
  size_t zbytes = off;
  int* gCursor = (int*)alloc((size_t)NBUCK * 4);
  int* bstart = (int*)alloc((size_t)(NBUCK + 1) * 4);
  unsigned int* pairs = (unsigned int*)alloc((size_t)NBUCK * BCAP * 4);
  int* indptr = (int*)alloc((size_t)(N_NODES + 1) * 4);
  int* esrc = (int*)alloc((size_t)EP * 4);
  int* esrc2 = (int*)alloc((size_t)EP * 4);
  int* perm = (int*)alloc((size_t)N_NODES * 4);
  int* pinv = (int*)alloc((size_t)N_NODES * 4);
  int* stp = (int*)alloc((size_t)N_NODES * 4);
  int* enp = (int*)alloc((size_t)N_NODES * 4);
  int* binCur = (int*)alloc((size_t)NBINS * 4);
  float* xp = (float*)alloc((size_t)N_NODES * 8 * 4);
  __half* t16a = (__half*)alloc((size_t)N_NODES * 64 * 2);
  __half* t16b = (__half*)alloc((size_t)N_NODES * 64 * 2);
  float* as_ = (float*)alloc((size_t)N_NODES * 16);
  float* ad_ = (float*)alloc((size_t)N_NODES * 16);
  float* tbuf = (float*)alloc((size_t)N_NODES * 32 * 4);
  float* part = (float*)alloc((size_t)NBLK2 * 128 * 4);
  float* scale = (float*)alloc(64 * 4);
  float* shift = (float*)alloc(64 * 4);
  float* wS1 = (float*)alloc(32 * 4);
  float* wD1 = (float*)alloc(32 * 4);
  float* wS2 = (float*)alloc(256 * 4);
  float* wD2 = (float*)alloc(256 * 4);
  float* wS3 = (float*)alloc(256 * 4);
  float* wD3 = (float*)alloc(256 * 4);
  __half* wf1 = (__half*)alloc((size_t)4 * 512 * 2);
  __half* wf2 = (__half*)alloc((size_t)32 * 512 * 2);
  __half* wf3 = (__half*)alloc((size_t)16 * 512 * 2);
  if (off > ws_size) return;

  hipMemsetAsync(pool, 0, zbytes, stream);

  k_prep<<<16 + cdiv(NBUCK, 256), 256, 0, stream>>>(W1, aS1, aD1, W2, aS2, aD2, W3, aS3, aD3,
                                                    wS1, wD1, wS2, wD2, wS3, wD3, wf1, wf2, wf3,
                                                    gCursor);
  k_bucket<<<cdiv(EP, BCHUNK), 256, 0, stream>>>(ei, gCursor, pairs);
  k_bscan<<<1, 1024, 0, stream>>>(gCursor, bstart);
  k_build<<<NBUCK, 256, 0, stream>>>(pairs, bstart, indptr, esrc, ghist);
  k_dscan<<<1, 64, 0, stream>>>(ghist, binCur);
  k_dscat<<<cdiv(N_NODES, 512), 256, 0, stream>>>(indptr, binCur, perm, pinv);
  k_etrans<<<cdiv(EP, 256), 256, 0, stream>>>(esrc, pinv, indptr, perm, esrc2, stp, enp);

  // ---- layer 1: permute x + dots; fused gather + MFMA -> t16a (permuted) ----
  k_prex1<<<cdiv(N_NODES, 256), 256, 0, stream>>>(x, perm, wS1, wD1, xp,
                                                  (float4*)as_, (float4*)ad_);
  k_aggp1<<<NBLK1, 256, 0, stream>>>(stp, enp, esrc2, xp, (const float4*)as_,
                                     (const float4*)ad_, wf1, b1, t16a, part);
  k_bnfin2<64><<<64, 256, 0, stream>>>(part, NBLK1, g1, be1, scale, shift);

  // ---- layer 2: dots on t16a (BN1); gather t16a + fold BN1 -> t16b (permuted) ----
  k_dots<<<cdiv(N_NODES, 4), 256, 0, stream>>>(t16a, scale, shift, wS2, wD2,
                                               (float4*)as_, (float4*)ad_);
  k_aggp<64, true><<<NBLK2, 256, 0, stream>>>(stp, enp, esrc2, t16a, (const float4*)as_,
                                              (const float4*)ad_, wf2, b2, scale, shift,
                                              perm, t16b, nullptr, part);
  k_bnfin2<64><<<64, 256, 0, stream>>>(part, NBLK2, g2, be2, scale, shift);

  // ---- layer 3: dots on t16b (BN2); gather t16b + fold BN2 -> tbuf fp32 (original) ----
  k_dots<<<cdiv(N_NODES, 4), 256, 0, stream>>>(t16b, scale, shift, wS3, wD3,
                                               (float4*)as_, (float4*)ad_);
  k_aggp<32, false><<<NBLK2, 256, 0, stream>>>(stp, enp, esrc2, t16b, (const float4*)as_,
                                               (const float4*)ad_, wf3, b3, scale, shift,
                                               perm, nullptr, tbuf, part);
  k_bnfin2<32><<<32, 256, 0, stream>>>(part, NBLK2, g3, be3, scale, shift);

  // ---- pool (BN3 on load) + MLP ----
  k_pool<<<cdiv(N_NODES, POOL_NPB), 256, 0, stream>>>(tbuf, batch, scale, shift, pool, cntg);
  k_mlp<<<1, 64, 0, stream>>>(pool, cntg, Wp1, bp1, Wp2, bp2, out);
}

// Round 18
// 382.857 us; speedup vs baseline: 1.0465x; 1.0465x over previous
//
#include <hip/hip_runtime.h>
#include <hip/hip_fp16.h>

#define N_NODES 100000
#define N_EDGES 1600000
#define EP (N_EDGES + N_NODES)
#define NG 64
#define NH 4
#define POOL_NPB 256
#define BSHIFT 7
#define BNODES 128
#define NBUCK 782   // cdiv(N_NODES, 128)
#define BCAP 3072   // per-bucket capacity (mean 2176)
#define BCHUNK 4096 // edges per k_bucket block (16 per thread, one-pass)
#define NBLK2 (N_NODES / 16)
#define NBLK1 (N_NODES / 32)
#define NBINS 64

static inline int cdiv(int a, int b) { return (a + b - 1) / b; }

typedef _Float16 half8 __attribute__((ext_vector_type(8)));
typedef float f32x4 __attribute__((ext_vector_type(4)));

__device__ __forceinline__ float lrelu(float x) { return x >= 0.f ? x : 0.2f * x; }

// ---------------- CSR build: one-pass bucket sort (register-staged; 416 blocks) ----------------
__global__ __launch_bounds__(256) void k_bucket(const int* __restrict__ ei,
                                                int* __restrict__ gCursor,
                                                unsigned int* __restrict__ pairs) {
  __shared__ int cnt[NBUCK];
  __shared__ int base[NBUCK];
  int tid = threadIdx.x;
  for (int b = tid; b < NBUCK; b += 256) cnt[b] = 0;
  __syncthreads();
  int e0 = blockIdx.x * BCHUNK;
  unsigned int stV[16];
  int stB[16];
#pragma unroll
  for (int i = 0; i < 16; i++) {
    int e = e0 + i * 256 + tid;
    stB[i] = -1;
    if (e < EP) {
      int d, s;
      if (e < N_EDGES) {
        d = __builtin_nontemporal_load(&ei[N_EDGES + e]);
        s = __builtin_nontemporal_load(&ei[e]);
      } else {
        d = s = e - N_EDGES;
      }
      int b = d >> BSHIFT;
      stV[i] = ((unsigned int)s << BSHIFT) | (unsigned int)(d & (BNODES - 1));
      stB[i] = b;
      atomicAdd(&cnt[b], 1);
    }
  }
  __syncthreads();
  for (int b = tid; b < NBUCK; b += 256) {
    int c = cnt[b];
    base[b] = c ? atomicAdd(&gCursor[b], c) : 0;
    cnt[b] = 0;  // reuse as cursor
  }
  __syncthreads();
#pragma unroll
  for (int i = 0; i < 16; i++) {
    if (stB[i] >= 0) {
      int r = atomicAdd(&cnt[stB[i]], 1);
      pairs[base[stB[i]] + r] = stV[i];
    }
  }
}

__global__ __launch_bounds__(1024) void k_bscan(const int* __restrict__ gCursor,
                                                int* __restrict__ bstart) {
  __shared__ int sh[1024];
  int t = threadIdx.x;
  int v = (t < NBUCK) ? (gCursor[t] - t * BCAP) : 0;
  sh[t] = v;
  __syncthreads();
  for (int off = 1; off < 1024; off <<= 1) {
    int add = (t >= off) ? sh[t - off] : 0;
    __syncthreads();
    sh[t] += add;
    __syncthreads();
  }
  if (t < NBUCK) {
    bstart[t] = sh[t] - v;
    if (t == NBUCK - 1) bstart[NBUCK] = sh[t];
  }
}

// per-bucket counting sort in LDS + degree histogram
__global__ __launch_bounds__(256) void k_build(const unsigned int* __restrict__ pairs,
                                               const int* __restrict__ bstart,
                                               int* __restrict__ indptr, int* __restrict__ esrc,
                                               int* __restrict__ ghist) {
  __shared__ int cnt[BNODES];
  __shared__ int exc[BNODES];
  __shared__ int ptr[BNODES];
  __shared__ int dh[NBINS];
  __shared__ int eLds[BCAP];
  int b = blockIdx.x;
  int tid = threadIdx.x;
  int obase = bstart[b];
  int nE = bstart[b + 1] - obase;
  int pbase = b * BCAP;
  if (tid < BNODES) cnt[tid] = 0;
  if (tid >= BNODES && tid < BNODES + NBINS) dh[tid - BNODES] = 0;
  __syncthreads();
  unsigned int stV[12];
#pragma unroll
  for (int i = 0; i < 12; i++) {
    int idx = i * 256 + tid;
    stV[i] = 0xFFFFFFFFu;
    if (idx < nE) {
      unsigned int v = pairs[pbase + idx];
      stV[i] = v;
      atomicAdd(&cnt[v & (BNODES - 1)], 1);
    }
  }
  __syncthreads();
  if (tid < BNODES) ptr[tid] = cnt[tid];
  __syncthreads();
  for (int off = 1; off < BNODES; off <<= 1) {
    int add = (tid < BNODES && tid >= off) ? ptr[tid - off] : 0;
    __syncthreads();
    if (tid < BNODES) ptr[tid] += add;
    __syncthreads();
  }
  if (tid < BNODES) {
    exc[tid] = ptr[tid] - cnt[tid];
    int n = (b << BSHIFT) + tid;
    if (n < N_NODES) {
      indptr[n] = obase + exc[tid];
      atomicAdd(&dh[min(cnt[tid], NBINS - 1)], 1);
    }
    cnt[tid] = 0;  // reuse as cursor
  }
  if (b == NBUCK - 1 && tid == 0) indptr[N_NODES] = bstart[NBUCK];
  __syncthreads();
  if (tid < NBINS && dh[tid]) atomicAdd(&ghist[tid], dh[tid]);
#pragma unroll
  for (int i = 0; i < 12; i++) {
    if (stV[i] != 0xFFFFFFFFu) {
      int ln = stV[i] & (BNODES - 1);
      int r = atomicAdd(&cnt[ln], 1);
      eLds[exc[ln] + r] = (int)(stV[i] >> BSHIFT);
    }
  }
  __syncthreads();
  for (int idx = tid; idx < nE; idx += 256) esrc[obase + idx] = eLds[idx];
}

// ---------------- degree-sort perm + inverse ----------------
__global__ void k_dscan(const int* __restrict__ ghist, int* __restrict__ binCur) {
  if (threadIdx.x == 0) {
    int acc = 0;
    for (int b = 0; b < NBINS; b++) {
      binCur[b] = acc;
      acc += ghist[b];
    }
  }
}

__global__ __launch_bounds__(256) void k_dscat(const int* __restrict__ indptr,
                                               int* __restrict__ binCur,
                                               int* __restrict__ perm, int* __restrict__ pinv) {
  __shared__ int cnt[NBINS];
  __shared__ int base[NBINS];
  int t = threadIdx.x;
  if (t < NBINS) cnt[t] = 0;
  __syncthreads();
  int binr[2], nr[2];
#pragma unroll
  for (int i = 0; i < 2; i++) {
    int n = blockIdx.x * 512 + i * 256 + t;
    binr[i] = -1;
    if (n < N_NODES) {
      int deg = indptr[n + 1] - indptr[n];
      binr[i] = min(deg, NBINS - 1);
      nr[i] = n;
      atomicAdd(&cnt[binr[i]], 1);
    }
  }
  __syncthreads();
  if (t < NBINS) {
    base[t] = cnt[t] ? atomicAdd(&binCur[t], cnt[t]) : 0;
    cnt[t] = 0;
  }
  __syncthreads();
#pragma unroll
  for (int i = 0; i < 2; i++) {
    if (binr[i] >= 0) {
      int r = atomicAdd(&cnt[binr[i]], 1);
      int pos = base[binr[i]] + r;
      perm[pos] = nr[i];
      pinv[nr[i]] = pos;
    }
  }
}

// ---------------- translate edges to permuted space + per-permuted-node extents ----------------
__global__ __launch_bounds__(256) void k_etrans(const int* __restrict__ esrc,
                                                const int* __restrict__ pinv,
                                                const int* __restrict__ indptr,
                                                const int* __restrict__ perm,
                                                int* __restrict__ esrc2,
                                                int* __restrict__ stp, int* __restrict__ enp) {
  int i = blockIdx.x * 256 + threadIdx.x;
  if (i < EP) esrc2[i] = pinv[esrc[i]];
  if (i < N_NODES) {
    int n = perm[i];
    stp[i] = indptr[n];
    enp[i] = indptr[n + 1];
  }
}

// ---------------- prep: attention-fold vectors + MFMA B-fragment packing + cursor init ----------------
template <int FIN, int D>
__device__ void wvec_impl(const float* __restrict__ W, const float* __restrict__ aS,
                          const float* __restrict__ aD, float* __restrict__ wS,
                          float* __restrict__ wD, int t) {
  if (t >= 4 * FIN) return;
  int h = t / FIN, k = t % FIN;
  float ss = 0.f, dd = 0.f;
  for (int d = 0; d < D; d++) {
    float w = W[k * (4 * D) + h * D + d];
    ss = fmaf(w, aS[h * D + d], ss);
    dd = fmaf(w, aD[h * D + d], dd);
  }
  wS[h * FIN + k] = ss;
  wD[h * FIN + k] = dd;
}

template <int D>
__device__ void wcvt_frag(const float* __restrict__ W, __half* __restrict__ wf, int frag, int l) {
  constexpr int NCT = D / 16;
  int kt = frag / NCT, ct = frag % NCT;
  half8 v;
#pragma unroll
  for (int j = 0; j < 8; j++) {
    int kk = kt * 32 + (l >> 4) * 8 + j;
    int k = kk >> 2, h = kk & 3;
    v[j] = (_Float16)W[k * (4 * D) + h * D + ct * 16 + (l & 15)];
  }
  *(half8*)(wf + (size_t)frag * 512 + l * 8) = v;
}

__global__ __launch_bounds__(256) void k_prep(const float* W1, const float* aS1, const float* aD1,
                                              const float* W2, const float* aS2, const float* aD2,
                                              const float* W3, const float* aS3, const float* aD3,
                                              float* wS1, float* wD1, float* wS2, float* wD2,
                                              float* wS3, float* wD3,
                                              __half* wf1, __half* wf2, __half* wf3,
                                              int* gCursor) {
  int b = blockIdx.x, t = threadIdx.x;
  int f = t >> 6, l = t & 63;
  if (b == 0) wvec_impl<8, 64>(W1, aS1, aD1, wS1, wD1, t);
  else if (b == 1) wvec_impl<64, 64>(W2, aS2, aD2, wS2, wD2, t);
  else if (b == 2) wvec_impl<64, 32>(W3, aS3, aD3, wS3, wD3, t);
  else if (b == 3) wcvt_frag<64>(W1, wf1, f, l);
  else if (b < 12) wcvt_frag<64>(W2, wf2, (b - 4) * 4 + f, l);
  else if (b < 16) wcvt_frag<32>(W3, wf3, (b - 12) * 4 + f, l);
  else {
    int idx = (b - 16) * 256 + t;
    if (idx < NBUCK) gCursor[idx] = idx * BCAP;
  }
}

// ---------------- layer-1 prep: permute x + attention dots (permuted space) ----------------
__global__ void k_prex1(const float* __restrict__ x, const int* __restrict__ perm,
                        const float* __restrict__ wS, const float* __restrict__ wD,
                        float* __restrict__ xp, float4* __restrict__ as4,
                        float4* __restrict__ ad4) {
  int p = blockIdx.x * blockDim.x + threadIdx.x;
  if (p >= N_NODES) return;
  int n = perm[p];
  float4 s = {0, 0, 0, 0}, d = {0, 0, 0, 0};
  float xv[8];
#pragma unroll
  for (int k = 0; k < 8; k++) {
    xv[k] = x[(size_t)n * 8 + k];
    s.x = fmaf(xv[k], wS[k], s.x);
    s.y = fmaf(xv[k], wS[8 + k], s.y);
    s.z = fmaf(xv[k], wS[16 + k], s.z);
    s.w = fmaf(xv[k], wS[24 + k], s.w);
    d.x = fmaf(xv[k], wD[k], d.x);
    d.y = fmaf(xv[k], wD[8 + k], d.y);
    d.z = fmaf(xv[k], wD[16 + k], d.z);
    d.w = fmaf(xv[k], wD[24 + k], d.w);
  }
  float4* xpv = (float4*)(xp + (size_t)p * 8);
  xpv[0] = make_float4(xv[0], xv[1], xv[2], xv[3]);
  xpv[1] = make_float4(xv[4], xv[5], xv[6], xv[7]);
  as4[p] = s;
  ad4[p] = d;
}

// ---------------- attention dots from permuted fp16 t (BN on the fly, read-only) ----------------
__global__ __launch_bounds__(256) void k_dots(const __half* __restrict__ t16,
                                              const float* __restrict__ scale,
                                              const float* __restrict__ shift,
                                              const float* __restrict__ wS,
                                              const float* __restrict__ wD,
                                              float4* __restrict__ as4, float4* __restrict__ ad4) {
  int lane = threadIdx.x & 63;
  int p = blockIdx.x * 4 + (threadIdx.x >> 6);
  if (p >= N_NODES) return;
  float v = fmaf(__half2float(t16[(size_t)p * 64 + lane]), scale[lane], shift[lane]);
  float p0 = v * wS[lane], p1 = v * wS[64 + lane], p2 = v * wS[128 + lane], p3 = v * wS[192 + lane];
  float q0 = v * wD[lane], q1 = v * wD[64 + lane], q2 = v * wD[128 + lane], q3 = v * wD[192 + lane];
#pragma unroll
  for (int off = 32; off; off >>= 1) {
    p0 += __shfl_xor(p0, off); p1 += __shfl_xor(p1, off);
    p2 += __shfl_xor(p2, off); p3 += __shfl_xor(p3, off);
    q0 += __shfl_xor(q0, off); q1 += __shfl_xor(q1, off);
    q2 += __shfl_xor(q2, off); q3 += __shfl_xor(q3, off);
  }
  if (lane == 0) {
    as4[p] = make_float4(p0, p1, p2, p3);
    ad4[p] = make_float4(q0, q1, q2, q3);
  }
}

// ---------------- fused layer-1: gather (8-lane groups, permuted space) + MFMA + BN partials ----------------
__global__ __launch_bounds__(256) void k_aggp1(const int* __restrict__ stp,
                                               const int* __restrict__ enp,
                                               const int* __restrict__ esrc2,
                                               const float* __restrict__ xp,
                                               const float4* __restrict__ as4,
                                               const float4* __restrict__ ad4,
                                               const __half* __restrict__ wfrag,
                                               const float* __restrict__ bias,
                                               __half* __restrict__ out16,
                                               float* __restrict__ part) {
  constexpr int GL = 8, NPW = 8, WB = NPW * (GL + 1);
  __shared__ int sOff[4 * WB];
  __shared__ float4 sW[4 * WB];
  __shared__ __align__(16) __half aT[32 * 40];
  int tid = threadIdx.x;
  int lane = tid & 63;
  int wv = tid >> 6;
  int q = lane & 7;
  int g = lane >> 3;
  int row = wv * 8 + g;
  int p = blockIdx.x * 32 + row;
  int e0 = stp[p], e1 = enp[p];
  float4 ad = ad4[p];
  int lbase = wv * WB + g * (GL + 1);
  const char* xb = (const char*)xp + q * 4;
  float s0 = 0.f, s1 = 0.f, s2 = 0.f, s3 = 0.f;
  float a0 = 0.f, a1 = 0.f, a2 = 0.f, a3 = 0.f;
  for (int c = e0; c < e1; c += GL) {
    int nc = min(GL, e1 - c);
    float w0 = 0.f, w1 = 0.f, w2 = 0.f, w3 = 0.f;
    int sB = 0;
    if (q < nc) {
      int sidx = esrc2[c + q];
      float4 av = as4[sidx];
      w0 = __expf(lrelu(av.x + ad.x));
      w1 = __expf(lrelu(av.y + ad.y));
      w2 = __expf(lrelu(av.z + ad.z));
      w3 = __expf(lrelu(av.w + ad.w));
      sB = sidx << 5;
    }
    s0 += w0; s1 += w1; s2 += w2; s3 += w3;
    sOff[lbase + q] = sB;
    sW[lbase + q] = make_float4(w0, w1, w2, w3);
    __builtin_amdgcn_wave_barrier();
    for (int i = 0; i < nc; ++i) {
      float4 w = sW[lbase + i];
      float xv = *(const float*)(xb + sOff[lbase + i]);
      a0 = fmaf(w.x, xv, a0);
      a1 = fmaf(w.y, xv, a1);
      a2 = fmaf(w.z, xv, a2);
      a3 = fmaf(w.w, xv, a3);
    }
    __builtin_amdgcn_wave_barrier();
  }
#pragma unroll
  for (int off = 1; off < GL; off <<= 1) {
    s0 += __shfl_xor(s0, off);
    s1 += __shfl_xor(s1, off);
    s2 += __shfl_xor(s2, off);
    s3 += __shfl_xor(s3, off);
  }
  float r0 = 1.f / (s0 + 1e-16f), r1 = 1.f / (s1 + 1e-16f);
  float r2 = 1.f / (s2 + 1e-16f), r3 = 1.f / (s3 + 1e-16f);
  __half2 p01 = __floats2half2_rn(a0 * r0, a1 * r1);
  __half2 p23 = __floats2half2_rn(a2 * r2, a3 * r3);
  uint2 pk = make_uint2(*(unsigned*)&p01, *(unsigned*)&p23);
  *(uint2*)&aT[row * 40 + q * 4] = pk;
  __syncthreads();
  int ct = wv;  // NCT = 4
  int m = lane & 15, kg = lane >> 4;
  half8 bv = *(const half8*)(wfrag + ((size_t)ct * 64 + lane) * 8);
  float bvs = bias[ct * 16 + m];
  float psum = 0.f, psq = 0.f;
#pragma unroll
  for (int tt = 0; tt < 2; tt++) {
    half8 avf = *(const half8*)&aT[(tt * 16 + m) * 40 + kg * 8];
    f32x4 cacc = (f32x4){0.f, 0.f, 0.f, 0.f};
    cacc = __builtin_amdgcn_mfma_f32_16x16x32_f16(avf, bv, cacc, 0, 0, 0);
#pragma unroll
    for (int j = 0; j < 4; j++) {
      int pr = blockIdx.x * 32 + tt * 16 + kg * 4 + j;
      float ov = fmaxf(fmaf(cacc[j], 0.25f, bvs), 0.f);
      out16[(size_t)pr * 64 + ct * 16 + m] = __float2half(ov);  // coalesced (permuted layout)
      psum += ov;
      psq = fmaf(ov, ov, psq);
    }
  }
  psum += __shfl_xor(psum, 16); psum += __shfl_xor(psum, 32);
  psq += __shfl_xor(psq, 16); psq += __shfl_xor(psq, 32);
  if (kg == 0) {
    part[(size_t)blockIdx.x * 128 + ct * 16 + m] = psum;
    part[(size_t)blockIdx.x * 128 + 64 + ct * 16 + m] = psq;
  }
}

// ---------------- fused gather + MFMA + BN partials (layers 2/3; permuted space) ----------------
template <int DOUT, bool OUTH>
__global__ __launch_bounds__(256) void k_aggp(const int* __restrict__ stp,
                                              const int* __restrict__ enp,
                                              const int* __restrict__ esrc2,
                                              const __half* __restrict__ xg,
                                              const float4* __restrict__ as4,
                                              const float4* __restrict__ ad4,
                                              const __half* __restrict__ wfrag,
                                              const float* __restrict__ bias,
                                              const float* __restrict__ scale,
                                              const float* __restrict__ shift,
                                              const int* __restrict__ perm,
                                              __half* __restrict__ out16,
                                              float* __restrict__ out32,
                                              float* __restrict__ part) {
  constexpr int NCT = DOUT / 16;
  constexpr int GL = 16, NPW = 4, WB = NPW * (GL + 1);
  __shared__ int sOff[4 * WB];
  __shared__ float4 sW[4 * WB];
  __shared__ __align__(16) __half aT[16 * 264];
  int tid = threadIdx.x;
  int lane = tid & 63;
  int wv = tid >> 6;
  int q = lane & 15;
  int g = lane >> 4;
  int row = wv * 4 + g;
  int p = blockIdx.x * 16 + row;
  int e0 = stp[p], e1 = enp[p];
  float4 ad = ad4[p];
  int lbase = wv * WB + g * (GL + 1);
  const char* xb = (const char*)xg + q * 8;
  float s0 = 0.f, s1 = 0.f, s2 = 0.f, s3 = 0.f;
  float a[4][4];
#pragma unroll
  for (int d = 0; d < 4; d++)
#pragma unroll
    for (int h = 0; h < 4; h++) a[d][h] = 0.f;

  for (int c = e0; c < e1; c += GL) {
    int nc = min(GL, e1 - c);
    float w0 = 0.f, w1 = 0.f, w2 = 0.f, w3 = 0.f;
    int sB = 0;
    if (q < nc) {
      int sidx = esrc2[c + q];
      float4 av = as4[sidx];
      w0 = __expf(lrelu(av.x + ad.x));
      w1 = __expf(lrelu(av.y + ad.y));
      w2 = __expf(lrelu(av.z + ad.z));
      w3 = __expf(lrelu(av.w + ad.w));
      sB = sidx << 7;
    }
    s0 += w0; s1 += w1; s2 += w2; s3 += w3;
    sOff[lbase + q] = sB;
    sW[lbase + q] = make_float4(w0, w1, w2, w3);
    __builtin_amdgcn_wave_barrier();
    for (int i = 0; i < nc; ++i) {
      float4 w = sW[lbase + i];
      uint2 px = *(const uint2*)(xb + sOff[lbase + i]);
      float2 f01 = __half22float2(*(const __half2*)&px.x);
      float2 f23 = __half22float2(*(const __half2*)&px.y);
      a[0][0] = fmaf(w.x, f01.x, a[0][0]); a[0][1] = fmaf(w.y, f01.x, a[0][1]);
      a[0][2] = fmaf(w.z, f01.x, a[0][2]); a[0][3] = fmaf(w.w, f01.x, a[0][3]);
      a[1][0] = fmaf(w.x, f01.y, a[1][0]); a[1][1] = fmaf(w.y, f01.y, a[1][1]);
      a[1][2] = fmaf(w.z, f01.y, a[1][2]); a[1][3] = fmaf(w.w, f01.y, a[1][3]);
      a[2][0] = fmaf(w.x, f23.x, a[2][0]); a[2][1] = fmaf(w.y, f23.x, a[2][1]);
      a[2][2] = fmaf(w.z, f23.x, a[2][2]); a[2][3] = fmaf(w.w, f23.x, a[2][3]);
      a[3][0] = fmaf(w.x, f23.y, a[3][0]); a[3][1] = fmaf(w.y, f23.y, a[3][1]);
      a[3][2] = fmaf(w.z, f23.y, a[3][2]); a[3][3] = fmaf(w.w, f23.y, a[3][3]);
    }
    __builtin_amdgcn_wave_barrier();
  }
#pragma unroll
  for (int off = 1; off < GL; off <<= 1) {
    s0 += __shfl_xor(s0, off);
    s1 += __shfl_xor(s1, off);
    s2 += __shfl_xor(s2, off);
    s3 += __shfl_xor(s3, off);
  }
  float r0 = 1.f / (s0 + 1e-16f), r1 = 1.f / (s1 + 1e-16f);
  float r2 = 1.f / (s2 + 1e-16f), r3 = 1.f / (s3 + 1e-16f);
  __half2 pp[8];
#pragma unroll
  for (int d = 0; d < 4; d++) {
    float sc = scale[q * 4 + d], sh = shift[q * 4 + d];
    pp[2 * d] = __floats2half2_rn(fmaf(a[d][0] * r0, sc, sh), fmaf(a[d][1] * r1, sc, sh));
    pp[2 * d + 1] = __floats2half2_rn(fmaf(a[d][2] * r2, sc, sh), fmaf(a[d][3] * r3, sc, sh));
  }
  uint4 lo = make_uint4(*(unsigned*)&pp[0], *(unsigned*)&pp[1], *(unsigned*)&pp[2], *(unsigned*)&pp[3]);
  uint4 hi = make_uint4(*(unsigned*)&pp[4], *(unsigned*)&pp[5], *(unsigned*)&pp[6], *(unsigned*)&pp[7]);
  *(uint4*)&aT[row * 264 + q * 16] = lo;
  *(uint4*)&aT[row * 264 + q * 16 + 8] = hi;
  __syncthreads();
  if (wv < NCT) {
    int ct = wv;
    int m = lane & 15, kg = lane >> 4;
    f32x4 cacc = (f32x4){0.f, 0.f, 0.f, 0.f};
#pragma unroll
    for (int kt = 0; kt < 8; kt++) {
      half8 avf = *(const half8*)&aT[m * 264 + kt * 32 + kg * 8];
      half8 bvf = *(const half8*)(wfrag + ((kt * NCT + ct) * 64 + lane) * 8);
      cacc = __builtin_amdgcn_mfma_f32_16x16x32_f16(avf, bvf, cacc, 0, 0, 0);
    }
    float bv = bias[ct * 16 + m];
    float psum = 0.f, psq = 0.f;
#pragma unroll
    for (int j = 0; j < 4; j++) {
      int pr = blockIdx.x * 16 + kg * 4 + j;
      float ov = fmaxf(fmaf(cacc[j], 0.25f, bv), 0.f);
      if constexpr (OUTH) {
        out16[(size_t)pr * DOUT + ct * 16 + m] = __float2half(ov);  // coalesced
      } else {
        int nr = perm[pr];  // back to original layout for pooling
        out32[(size_t)nr * DOUT + ct * 16 + m] = ov;
      }
      psum += ov;
      psq = fmaf(ov, ov, psq);
    }
    psum += __shfl_xor(psum, 16); psum += __shfl_xor(psum, 32);
    psq += __shfl_xor(psq, 16); psq += __shfl_xor(psq, 32);
    if (kg == 0) {
      part[(size_t)blockIdx.x * (2 * DOUT) + ct * 16 + m] = psum;
      part[(size_t)blockIdx.x * (2 * DOUT) + DOUT + ct * 16 + m] = psq;
    }
  }
}

// ---------------- BN finalize from per-block partials: grid = C blocks ----------------
template <int C>
__global__ __launch_bounds__(256) void k_bnfin2(const float* __restrict__ part, int nb,
                                                const float* __restrict__ g,
                                                const float* __restrict__ be,
                                                float* __restrict__ scale,
                                                float* __restrict__ shift) {
  int c = blockIdx.x;
  int t = threadIdx.x;
  float s = 0.f, q = 0.f;
  for (int b = t; b < nb; b += 256) {
    s += part[(size_t)b * (2 * C) + c];
    q += part[(size_t)b * (2 * C) + C + c];
  }
  __shared__ float sh[512];
  sh[t] = s;
  sh[256 + t] = q;
  __syncthreads();
  for (int step = 128; step; step >>= 1) {
    if (t < step) {
      sh[t] += sh[t + step];
      sh[256 + t] += sh[256 + t + step];
    }
    __syncthreads();
  }
  if (t == 0) {
    float mean = sh[0] / (float)N_NODES;
    float var = sh[256] / (float)N_NODES - mean * mean;
    float sc = g[c] * rsqrtf(var + 1e-5f);
    scale[c] = sc;
    shift[c] = be[c] - mean * sc;
  }
}

// ---------------- pooling (applies layer-3 BN on load; batch sorted, original layout) ----------------
__global__ __launch_bounds__(256) void k_pool(const float* __restrict__ f3,
                                              const int* __restrict__ batch,
                                              const float* __restrict__ scale,
                                              const float* __restrict__ shift,
                                              float* __restrict__ pool,
                                              float* __restrict__ cntg) {
  __shared__ float acc[NG][33];
  int t = threadIdx.x;
  for (int i = t; i < NG * 33; i += 256) ((float*)acc)[i] = 0.f;
  __syncthreads();
  int c = t & 31, rg = t >> 5;
  float sc = scale[c], sh = shift[c];
  int n0 = blockIdx.x * POOL_NPB;
  int n1 = min(N_NODES, n0 + POOL_NPB);
  float r = 0.f, rc = 0.f;
  int gcur = -1;
  for (int n = n0 + rg; n < n1; n += 8) {
    int g = batch[n];
    if (g != gcur) {
      if (gcur >= 0) {
        atomicAdd(&acc[gcur][c], r);
        if (c == 0) atomicAdd(&acc[gcur][32], rc);
      }
      gcur = g;
      r = 0.f;
      rc = 0.f;
    }
    r += fmaf(f3[(size_t)n * 32 + c], sc, sh);
    rc += 1.f;
  }
  if (gcur >= 0) {
    atomicAdd(&acc[gcur][c], r);
    if (c == 0) atomicAdd(&acc[gcur][32], rc);
  }
  __syncthreads();
  for (int i = t; i < NG * 32; i += 256) {
    int g = i >> 5, cc = i & 31;
    float v = acc[g][cc];
    if (v != 0.f) atomicAdd(&pool[i], v);
  }
  for (int g = t; g < NG; g += 256) {
    float v = acc[g][32];
    if (v != 0.f) atomicAdd(&cntg[g], v);
  }
}

__global__ void k_mlp(const float* __restrict__ pool, const float* __restrict__ cntg,
                      const float* __restrict__ Wp1, const float* __restrict__ bp1,
                      const float* __restrict__ Wp2, const float* __restrict__ bp2,
                      float* __restrict__ out) {
  int g = threadIdx.x;
  if (g >= NG) return;
  float inv = 1.f / fmaxf(cntg[g], 1.f);
  float p[32];
#pragma unroll
  for (int c = 0; c < 32; c++) p[c] = pool[g * 32 + c] * inv;
  float o = bp2[0];
  for (int j = 0; j < 16; j++) {
    float hsum = bp1[j];
#pragma unroll
    for (int c = 0; c < 32; c++) hsum = fmaf(p[c], Wp1[c * 16 + j], hsum);
    o = fmaf(fmaxf(hsum, 0.f), Wp2[j], o);
  }
  out[g] = o;
}

extern "C" void kernel_launch(void* const* d_in, const int* in_sizes, int n_in,
                              void* d_out, int out_size, void* d_ws, size_t ws_size,
                              hipStream_t stream) {
  const float* x = (const float*)d_in[0];
  const int* ei = (const int*)d_in[1];
  const int* batch = (const int*)d_in[2];
  const float* W1 = (const float*)d_in[3];
  const float* aS1 = (const float*)d_in[4];
  const float* aD1 = (const float*)d_in[5];
  const float* b1 = (const float*)d_in[6];
  const float* g1 = (const float*)d_in[7];
  const float* be1 = (const float*)d_in[8];
  const float* W2 = (const float*)d_in[9];
  const float* aS2 = (const float*)d_in[10];
  const float* aD2 = (const float*)d_in[11];
  const float* b2 = (const float*)d_in[12];
  const float* g2 = (const float*)d_in[13];
  const float* be2 = (const float*)d_in[14];
  const float* W3 = (const float*)d_in[15];
  const float* aS3 = (const float*)d_in[16];
  const float* aD3 = (const float*)d_in[17];
  const float* b3 = (const float*)d_in[18];
  const float* g3 = (const float*)d_in[19];
  const float* be3 = (const float*)d_in[20];
  const float* Wp1 = (const float*)d_in[21];
  const float* bp1 = (const float*)d_in[22];
  const float* Wp2 = (const float*)d_in[23];
  const float* bp2 = (const float*)d_in[24];
  float* out = (float*)d_out;

  size_t off = 0;
  auto alloc = [&](size_t bytes) -> void* {
    void* p = (char*)d_ws + off;
    off += (bytes + 255) & ~(size_t)255;
    return p;
  };
  // zeroed region (single memset): pool, cntg, ghist
  float* pool = (float*)alloc((size_t)NG * 32 * 4);
  float* cntg = (float*)alloc((size_t)NG * 4);
  int* ghist = (int*)alloc((size_t)NBINS * 4);
  size_t zbytes = off;
  int* gCursor = (int*)alloc((size_t)NBUCK * 4);
  int* bstart = (int*)alloc((size_t)(NBUCK + 1) * 4);
  unsigned int* pairs = (unsigned int*)alloc((size_t)NBUCK * BCAP * 4);
  int* indptr = (int*)alloc((size_t)(N_NODES + 1) * 4);
  int* esrc = (int*)alloc((size_t)EP * 4);
  int* esrc2 = (int*)alloc((size_t)EP * 4);
  int* perm = (int*)alloc((size_t)N_NODES * 4);
  int* pinv = (int*)alloc((size_t)N_NODES * 4);
  int* stp = (int*)alloc((size_t)N_NODES * 4);
  int* enp = (int*)alloc((size_t)N_NODES * 4);
  int* binCur = (int*)alloc((size_t)NBINS * 4);
  float* xp = (float*)alloc((size_t)N_NODES * 8 * 4);
  __half* t16a = (__half*)alloc((size_t)N_NODES * 64 * 2);
  __half* t16b = (__half*)alloc((size_t)N_NODES * 64 * 2);
  float* as_ = (float*)alloc((size_t)N_NODES * 16);
  float* ad_ = (float*)alloc((size_t)N_NODES * 16);
  float* tbuf = (float*)alloc((size_t)N_NODES * 32 * 4);
  float* part = (float*)alloc((size_t)NBLK2 * 128 * 4);
  float* scale = (float*)alloc(64 * 4);
  float* shift = (float*)alloc(64 * 4);
  float* wS1 = (float*)alloc(32 * 4);
  float* wD1 = (float*)alloc(32 * 4);
  float* wS2 = (float*)alloc(256 * 4);
  float* wD2 = (float*)alloc(256 * 4);
  float* wS3 = (float*)alloc(256 * 4);
  float* wD3 = (float*)alloc(256 * 4);
  __half* wf1 = (__half*)alloc((size_t)4 * 512 * 2);
  __half* wf2 = (__half*)alloc((size_t)32 * 512 * 2);
  __half* wf3 = (__half*)alloc((size_t)16 * 512 * 2);
  if (off > ws_size) return;

  hipMemsetAsync(pool, 0, zbytes, stream);

  k_prep<<<16 + cdiv(NBUCK, 256), 256, 0, stream>>>(W1, aS1, aD1, W2, aS2, aD2, W3, aS3, aD3,
                                                    wS1, wD1, wS2, wD2, wS3, wD3, wf1, wf2, wf3,
                                                    gCursor);
  k_bucket<<<cdiv(EP, BCHUNK), 256, 0, stream>>>(ei, gCursor, pairs);
  k_bscan<<<1, 1024, 0, stream>>>(gCursor, bstart);
  k_build<<<NBUCK, 256, 0, stream>>>(pairs, bstart, indptr, esrc, ghist);
  k_dscan<<<1, 64, 0, stream>>>(ghist, binCur);
  k_dscat<<<cdiv(N_NODES, 512), 256, 0, stream>>>(indptr, binCur, perm, pinv);
  k_etrans<<<cdiv(EP, 256), 256, 0, stream>>>(esrc, pinv, indptr, perm, esrc2, stp, enp);

  // ---- layer 1: permute x + dots; fused gather + MFMA -> t16a (permuted) ----
  k_prex1<<<cdiv(N_NODES, 256), 256, 0, stream>>>(x, perm, wS1, wD1, xp,
                                                  (float4*)as_, (float4*)ad_);
  k_aggp1<<<NBLK1, 256, 0, stream>>>(stp, enp, esrc2, xp, (const float4*)as_,
                                     (const float4*)ad_, wf1, b1, t16a, part);
  k_bnfin2<64><<<64, 256, 0, stream>>>(part, NBLK1, g1, be1, scale, shift);

  // ---- layer 2: dots on t16a (BN1); gather t16a + fold BN1 -> t16b (permuted) ----
  k_dots<<<cdiv(N_NODES, 4), 256, 0, stream>>>(t16a, scale, shift, wS2, wD2,
                                               (float4*)as_, (float4*)ad_);
  k_aggp<64, true><<<NBLK2, 256, 0, stream>>>(stp, enp, esrc2, t16a, (const float4*)as_,
                                              (const float4*)ad_, wf2, b2, scale, shift,
                                              perm, t16b, nullptr, part);
  k_bnfin2<64><<<64, 256, 0, stream>>>(part, NBLK2, g2, be2, scale, shift);

  // ---- layer 3: dots on t16b (BN2); gather t16b + fold BN2 -> tbuf fp32 (original) ----
  k_dots<<<cdiv(N_NODES, 4), 256, 0, stream>>>(t16b, scale, shift, wS3, wD3,
                                               (float4*)as_, (float4*)ad_);
  k_aggp<32, false><<<NBLK2, 256, 0, stream>>>(stp, enp, esrc2, t16b, (const float4*)as_,
                                               (const float4*)ad_, wf3, b3, scale, shift,
                                               perm, nullptr, tbuf, part);
  k_bnfin2<32><<<32, 256, 0, stream>>>(part, NBLK2, g3, be3, scale, shift);

  // ---- pool (BN3 on load) + MLP ----
  k_pool<<<cdiv(N_NODES, POOL_NPB), 256, 0, stream>>>(tbuf, batch, scale, shift, pool, cntg);
  k_mlp<<<1, 64, 0, stream>>>(pool, cntg, Wp1, bp1, Wp2, bp2, out);
}

// Round 19
// 373.675 us; speedup vs baseline: 1.0722x; 1.0246x over previous
//
#include <hip/hip_runtime.h>
#include <hip/hip_fp16.h>

#define N_NODES 100000
#define N_EDGES 1600000
#define EP (N_EDGES + N_NODES)
#define NG 64
#define NH 4
#define POOL_NPB 256
#define BSHIFT 7
#define BNODES 128
#define NBUCK 782   // cdiv(N_NODES, 128)
#define BCAP 3072   // per-bucket capacity (mean 2176)
#define BCHUNK 4096 // edges per k_bucket block (16 per thread, one-pass)
#define NBLK2 (N_NODES / 16)
#define NBLK1 (N_NODES / 32)
#define NBINS 64

static inline int cdiv(int a, int b) { return (a + b - 1) / b; }

typedef _Float16 half8 __attribute__((ext_vector_type(8)));
typedef float f32x4 __attribute__((ext_vector_type(4)));

__device__ __forceinline__ float lrelu(float x) { return x >= 0.f ? x : 0.2f * x; }

// ---------------- CSR build: one-pass bucket sort (register-staged; 416 blocks) ----------------
__global__ __launch_bounds__(256) void k_bucket(const int* __restrict__ ei,
                                                int* __restrict__ gCursor,
                                                unsigned int* __restrict__ pairs) {
  __shared__ int cnt[NBUCK];
  __shared__ int base[NBUCK];
  int tid = threadIdx.x;
  for (int b = tid; b < NBUCK; b += 256) cnt[b] = 0;
  __syncthreads();
  int e0 = blockIdx.x * BCHUNK;
  unsigned int stV[16];
  int stB[16];
#pragma unroll
  for (int i = 0; i < 16; i++) {
    int e = e0 + i * 256 + tid;
    stB[i] = -1;
    if (e < EP) {
      int d, s;
      if (e < N_EDGES) {
        d = __builtin_nontemporal_load(&ei[N_EDGES + e]);
        s = __builtin_nontemporal_load(&ei[e]);
      } else {
        d = s = e - N_EDGES;
      }
      int b = d >> BSHIFT;
      stV[i] = ((unsigned int)s << BSHIFT) | (unsigned int)(d & (BNODES - 1));
      stB[i] = b;
      atomicAdd(&cnt[b], 1);
    }
  }
  __syncthreads();
  for (int b = tid; b < NBUCK; b += 256) {
    int c = cnt[b];
    base[b] = c ? atomicAdd(&gCursor[b], c) : 0;
    cnt[b] = 0;  // reuse as cursor
  }
  __syncthreads();
#pragma unroll
  for (int i = 0; i < 16; i++) {
    if (stB[i] >= 0) {
      int r = atomicAdd(&cnt[stB[i]], 1);
      pairs[base[stB[i]] + r] = stV[i];
    }
  }
}

__global__ __launch_bounds__(1024) void k_bscan(const int* __restrict__ gCursor,
                                                int* __restrict__ bstart) {
  __shared__ int sh[1024];
  int t = threadIdx.x;
  int v = (t < NBUCK) ? (gCursor[t] - t * BCAP) : 0;
  sh[t] = v;
  __syncthreads();
  for (int off = 1; off < 1024; off <<= 1) {
    int add = (t >= off) ? sh[t - off] : 0;
    __syncthreads();
    sh[t] += add;
    __syncthreads();
  }
  if (t < NBUCK) {
    bstart[t] = sh[t] - v;
    if (t == NBUCK - 1) bstart[NBUCK] = sh[t];
  }
}

// per-bucket counting sort in LDS + degree histogram
__global__ __launch_bounds__(256) void k_build(const unsigned int* __restrict__ pairs,
                                               const int* __restrict__ bstart,
                                               int* __restrict__ indptr, int* __restrict__ esrc,
                                               int* __restrict__ ghist) {
  __shared__ int cnt[BNODES];
  __shared__ int exc[BNODES];
  __shared__ int ptr[BNODES];
  __shared__ int dh[NBINS];
  __shared__ int eLds[BCAP];
  int b = blockIdx.x;
  int tid = threadIdx.x;
  int obase = bstart[b];
  int nE = bstart[b + 1] - obase;
  int pbase = b * BCAP;
  if (tid < BNODES) cnt[tid] = 0;
  if (tid >= BNODES && tid < BNODES + NBINS) dh[tid - BNODES] = 0;
  __syncthreads();
  unsigned int stV[12];
#pragma unroll
  for (int i = 0; i < 12; i++) {
    int idx = i * 256 + tid;
    stV[i] = 0xFFFFFFFFu;
    if (idx < nE) {
      unsigned int v = pairs[pbase + idx];
      stV[i] = v;
      atomicAdd(&cnt[v & (BNODES - 1)], 1);
    }
  }
  __syncthreads();
  if (tid < BNODES) ptr[tid] = cnt[tid];
  __syncthreads();
  for (int off = 1; off < BNODES; off <<= 1) {
    int add = (tid < BNODES && tid >= off) ? ptr[tid - off] : 0;
    __syncthreads();
    if (tid < BNODES) ptr[tid] += add;
    __syncthreads();
  }
  if (tid < BNODES) {
    exc[tid] = ptr[tid] - cnt[tid];
    int n = (b << BSHIFT) + tid;
    if (n < N_NODES) {
      indptr[n] = obase + exc[tid];
      atomicAdd(&dh[min(cnt[tid], NBINS - 1)], 1);
    }
    cnt[tid] = 0;  // reuse as cursor
  }
  if (b == NBUCK - 1 && tid == 0) indptr[N_NODES] = bstart[NBUCK];
  __syncthreads();
  if (tid < NBINS && dh[tid]) atomicAdd(&ghist[tid], dh[tid]);
#pragma unroll
  for (int i = 0; i < 12; i++) {
    if (stV[i] != 0xFFFFFFFFu) {
      int ln = stV[i] & (BNODES - 1);
      int r = atomicAdd(&cnt[ln], 1);
      eLds[exc[ln] + r] = (int)(stV[i] >> BSHIFT);
    }
  }
  __syncthreads();
  for (int idx = tid; idx < nE; idx += 256) esrc[obase + idx] = eLds[idx];
}

// ---------------- degree-sort perm (DESCENDING degree: LPT block scheduling) + inverse ----------------
__global__ __launch_bounds__(256) void k_dscat(const int* __restrict__ ghist,
                                               const int* __restrict__ indptr,
                                               int* __restrict__ binCur,
                                               int* __restrict__ perm, int* __restrict__ pinv) {
  __shared__ int cnt[NBINS];
  __shared__ int base[NBINS];
  int t = threadIdx.x;
  if (t < NBINS) cnt[t] = 0;
  __syncthreads();
  int binr[2], nr[2];
#pragma unroll
  for (int i = 0; i < 2; i++) {
    int n = blockIdx.x * 512 + i * 256 + t;
    binr[i] = -1;
    if (n < N_NODES) {
      int deg = indptr[n + 1] - indptr[n];
      binr[i] = min(deg, NBINS - 1);
      nr[i] = n;
      atomicAdd(&cnt[binr[i]], 1);
    }
  }
  __syncthreads();
  if (t < NBINS) {
    if (cnt[t]) {
      // descending prefix: bins with HIGHER degree come first
      int pref = 0;
      for (int b2 = NBINS - 1; b2 > t; b2--) pref += ghist[b2];
      base[t] = pref + atomicAdd(&binCur[t], cnt[t]);
    }
    cnt[t] = 0;
  }
  __syncthreads();
#pragma unroll
  for (int i = 0; i < 2; i++) {
    if (binr[i] >= 0) {
      int r = atomicAdd(&cnt[binr[i]], 1);
      int pos = base[binr[i]] + r;
      perm[pos] = nr[i];
      pinv[nr[i]] = pos;
    }
  }
}

// ---------------- translate edges to permuted space + per-permuted-node extents ----------------
__global__ __launch_bounds__(256) void k_etrans(const int* __restrict__ esrc,
                                                const int* __restrict__ pinv,
                                                const int* __restrict__ indptr,
                                                const int* __restrict__ perm,
                                                int* __restrict__ esrc2,
                                                int* __restrict__ stp, int* __restrict__ enp) {
  int i = blockIdx.x * 256 + threadIdx.x;
  if (i < EP) esrc2[i] = pinv[esrc[i]];
  if (i < N_NODES) {
    int n = perm[i];
    stp[i] = indptr[n];
    enp[i] = indptr[n + 1];
  }
}

// ---------------- prep: attention-fold vectors + MFMA B-fragment packing + cursor init ----------------
template <int FIN, int D>
__device__ void wvec_impl(const float* __restrict__ W, const float* __restrict__ aS,
                          const float* __restrict__ aD, float* __restrict__ wS,
                          float* __restrict__ wD, int t) {
  if (t >= 4 * FIN) return;
  int h = t / FIN, k = t % FIN;
  float ss = 0.f, dd = 0.f;
  for (int d = 0; d < D; d++) {
    float w = W[k * (4 * D) + h * D + d];
    ss = fmaf(w, aS[h * D + d], ss);
    dd = fmaf(w, aD[h * D + d], dd);
  }
  wS[h * FIN + k] = ss;
  wD[h * FIN + k] = dd;
}

template <int D>
__device__ void wcvt_frag(const float* __restrict__ W, __half* __restrict__ wf, int frag, int l) {
  constexpr int NCT = D / 16;
  int kt = frag / NCT, ct = frag % NCT;
  half8 v;
#pragma unroll
  for (int j = 0; j < 8; j++) {
    int kk = kt * 32 + (l >> 4) * 8 + j;
    int k = kk >> 2, h = kk & 3;
    v[j] = (_Float16)W[k * (4 * D) + h * D + ct * 16 + (l & 15)];
  }
  *(half8*)(wf + (size_t)frag * 512 + l * 8) = v;
}

__global__ __launch_bounds__(256) void k_prep(const float* W1, const float* aS1, const float* aD1,
                                              const float* W2, const float* aS2, const float* aD2,
                                              const float* W3, const float* aS3, const float* aD3,
                                              float* wS1, float* wD1, float* wS2, float* wD2,
                                              float* wS3, float* wD3,
                                              __half* wf1, __half* wf2, __half* wf3,
                                              int* gCursor) {
  int b = blockIdx.x, t = threadIdx.x;
  int f = t >> 6, l = t & 63;
  if (b == 0) wvec_impl<8, 64>(W1, aS1, aD1, wS1, wD1, t);
  else if (b == 1) wvec_impl<64, 64>(W2, aS2, aD2, wS2, wD2, t);
  else if (b == 2) wvec_impl<64, 32>(W3, aS3, aD3, wS3, wD3, t);
  else if (b == 3) wcvt_frag<64>(W1, wf1, f, l);
  else if (b < 12) wcvt_frag<64>(W2, wf2, (b - 4) * 4 + f, l);
  else if (b < 16) wcvt_frag<32>(W3, wf3, (b - 12) * 4 + f, l);
  else {
    int idx = (b - 16) * 256 + t;
    if (idx < NBUCK) gCursor[idx] = idx * BCAP;
  }
}

// ---------------- layer-1 prep: permute x + attention dots (permuted space) ----------------
__global__ void k_prex1(const float* __restrict__ x, const int* __restrict__ perm,
                        const float* __restrict__ wS, const float* __restrict__ wD,
                        float* __restrict__ xp, float4* __restrict__ as4,
                        float4* __restrict__ ad4) {
  int p = blockIdx.x * blockDim.x + threadIdx.x;
  if (p >= N_NODES) return;
  int n = perm[p];
  float4 s = {0, 0, 0, 0}, d = {0, 0, 0, 0};
  float xv[8];
#pragma unroll
  for (int k = 0; k < 8; k++) {
    xv[k] = x[(size_t)n * 8 + k];
    s.x = fmaf(xv[k], wS[k], s.x);
    s.y = fmaf(xv[k], wS[8 + k], s.y);
    s.z = fmaf(xv[k], wS[16 + k], s.z);
    s.w = fmaf(xv[k], wS[24 + k], s.w);
    d.x = fmaf(xv[k], wD[k], d.x);
    d.y = fmaf(xv[k], wD[8 + k], d.y);
    d.z = fmaf(xv[k], wD[16 + k], d.z);
    d.w = fmaf(xv[k], wD[24 + k], d.w);
  }
  float4* xpv = (float4*)(xp + (size_t)p * 8);
  xpv[0] = make_float4(xv[0], xv[1], xv[2], xv[3]);
  xpv[1] = make_float4(xv[4], xv[5], xv[6], xv[7]);
  as4[p] = s;
  ad4[p] = d;
}

// ---------------- attention dots from permuted fp16 t (BN on the fly, read-only) ----------------
__global__ __launch_bounds__(256) void k_dots(const __half* __restrict__ t16,
                                              const float* __restrict__ scale,
                                              const float* __restrict__ shift,
                                              const float* __restrict__ wS,
                                              const float* __restrict__ wD,
                                              float4* __restrict__ as4, float4* __restrict__ ad4) {
  int lane = threadIdx.x & 63;
  int p = blockIdx.x * 4 + (threadIdx.x >> 6);
  if (p >= N_NODES) return;
  float v = fmaf(__half2float(t16[(size_t)p * 64 + lane]), scale[lane], shift[lane]);
  float p0 = v * wS[lane], p1 = v * wS[64 + lane], p2 = v * wS[128 + lane], p3 = v * wS[192 + lane];
  float q0 = v * wD[lane], q1 = v * wD[64 + lane], q2 = v * wD[128 + lane], q3 = v * wD[192 + lane];
#pragma unroll
  for (int off = 32; off; off >>= 1) {
    p0 += __shfl_xor(p0, off); p1 += __shfl_xor(p1, off);
    p2 += __shfl_xor(p2, off); p3 += __shfl_xor(p3, off);
    q0 += __shfl_xor(q0, off); q1 += __shfl_xor(q1, off);
    q2 += __shfl_xor(q2, off); q3 += __shfl_xor(q3, off);
  }
  if (lane == 0) {
    as4[p] = make_float4(p0, p1, p2, p3);
    ad4[p] = make_float4(q0, q1, q2, q3);
  }
}

// ---------------- fused layer-1: gather (8-lane groups, permuted space) + MFMA + BN partials ----------------
__global__ __launch_bounds__(256) void k_aggp1(const int* __restrict__ stp,
                                               const int* __restrict__ enp,
                                               const int* __restrict__ esrc2,
                                               const float* __restrict__ xp,
                                               const float4* __restrict__ as4,
                                               const float4* __restrict__ ad4,
                                               const __half* __restrict__ wfrag,
                                               const float* __restrict__ bias,
                                               __half* __restrict__ out16,
                                               float* __restrict__ part) {
  constexpr int GL = 8, NPW = 8, WB = NPW * (GL + 1);
  __shared__ int sOff[4 * WB];
  __shared__ float4 sW[4 * WB];
  __shared__ __align__(16) __half aT[32 * 40];
  int tid = threadIdx.x;
  int lane = tid & 63;
  int wv = tid >> 6;
  int q = lane & 7;
  int g = lane >> 3;
  int row = wv * 8 + g;
  int p = blockIdx.x * 32 + row;
  int e0 = stp[p], e1 = enp[p];
  float4 ad = ad4[p];
  int lbase = wv * WB + g * (GL + 1);
  const char* xb = (const char*)xp + q * 4;
  float s0 = 0.f, s1 = 0.f, s2 = 0.f, s3 = 0.f;
  float a0 = 0.f, a1 = 0.f, a2 = 0.f, a3 = 0.f;
  for (int c = e0; c < e1; c += GL) {
    int nc = min(GL, e1 - c);
    float w0 = 0.f, w1 = 0.f, w2 = 0.f, w3 = 0.f;
    int sB = 0;
    if (q < nc) {
      int sidx = esrc2[c + q];
      float4 av = as4[sidx];
      w0 = __expf(lrelu(av.x + ad.x));
      w1 = __expf(lrelu(av.y + ad.y));
      w2 = __expf(lrelu(av.z + ad.z));
      w3 = __expf(lrelu(av.w + ad.w));
      sB = sidx << 5;
    }
    s0 += w0; s1 += w1; s2 += w2; s3 += w3;
    sOff[lbase + q] = sB;
    sW[lbase + q] = make_float4(w0, w1, w2, w3);
    __builtin_amdgcn_wave_barrier();
    for (int i = 0; i < nc; ++i) {
      float4 w = sW[lbase + i];
      float xv = *(const float*)(xb + sOff[lbase + i]);
      a0 = fmaf(w.x, xv, a0);
      a1 = fmaf(w.y, xv, a1);
      a2 = fmaf(w.z, xv, a2);
      a3 = fmaf(w.w, xv, a3);
    }
    __builtin_amdgcn_wave_barrier();
  }
#pragma unroll
  for (int off = 1; off < GL; off <<= 1) {
    s0 += __shfl_xor(s0, off);
    s1 += __shfl_xor(s1, off);
    s2 += __shfl_xor(s2, off);
    s3 += __shfl_xor(s3, off);
  }
  float r0 = 1.f / (s0 + 1e-16f), r1 = 1.f / (s1 + 1e-16f);
  float r2 = 1.f / (s2 + 1e-16f), r3 = 1.f / (s3 + 1e-16f);
  __half2 p01 = __floats2half2_rn(a0 * r0, a1 * r1);
  __half2 p23 = __floats2half2_rn(a2 * r2, a3 * r3);
  uint2 pk = make_uint2(*(unsigned*)&p01, *(unsigned*)&p23);
  *(uint2*)&aT[row * 40 + q * 4] = pk;
  __syncthreads();
  int ct = wv;  // NCT = 4
  int m = lane & 15, kg = lane >> 4;
  half8 bv = *(const half8*)(wfrag + ((size_t)ct * 64 + lane) * 8);
  float bvs = bias[ct * 16 + m];
  float psum = 0.f, psq = 0.f;
#pragma unroll
  for (int tt = 0; tt < 2; tt++) {
    half8 avf = *(const half8*)&aT[(tt * 16 + m) * 40 + kg * 8];
    f32x4 cacc = (f32x4){0.f, 0.f, 0.f, 0.f};
    cacc = __builtin_amdgcn_mfma_f32_16x16x32_f16(avf, bv, cacc, 0, 0, 0);
#pragma unroll
    for (int j = 0; j < 4; j++) {
      int pr = blockIdx.x * 32 + tt * 16 + kg * 4 + j;
      float ov = fmaxf(fmaf(cacc[j], 0.25f, bvs), 0.f);
      out16[(size_t)pr * 64 + ct * 16 + m] = __float2half(ov);  // coalesced (permuted layout)
      psum += ov;
      psq = fmaf(ov, ov, psq);
    }
  }
  psum += __shfl_xor(psum, 16); psum += __shfl_xor(psum, 32);
  psq += __shfl_xor(psq, 16); psq += __shfl_xor(psq, 32);
  if (kg == 0) {
    part[(size_t)blockIdx.x * 128 + ct * 16 + m] = psum;
    part[(size_t)blockIdx.x * 128 + 64 + ct * 16 + m] = psq;
  }
}

// ---------------- fused gather + MFMA + BN partials (layers 2/3; permuted space) ----------------
template <int DOUT, bool OUTH>
__global__ __launch_bounds__(256) void k_aggp(const int* __restrict__ stp,
                                              const int* __restrict__ enp,
                                              const int* __restrict__ esrc2,
                                              const __half* __restrict__ xg,
                                              const float4* __restrict__ as4,
                                              const float4* __restrict__ ad4,
                                              const __half* __restrict__ wfrag,
                                              const float* __restrict__ bias,
                                              const float* __restrict__ scale,
                                              const float* __restrict__ shift,
                                              const int* __restrict__ perm,
                                              __half* __restrict__ out16,
                                              float* __restrict__ out32,
                                              float* __restrict__ part) {
  constexpr int NCT = DOUT / 16;
  constexpr int GL = 16, NPW = 4, WB = NPW * (GL + 1);
  __shared__ int sOff[4 * WB];
  __shared__ float4 sW[4 * WB];
  __shared__ __align__(16) __half aT[16 * 264];
  int tid = threadIdx.x;
  int lane = tid & 63;
  int wv = tid >> 6;
  int q = lane & 15;
  int g = lane >> 4;
  int row = wv * 4 + g;
  int p = blockIdx.x * 16 + row;
  int e0 = stp[p], e1 = enp[p];
  float4 ad = ad4[p];
  int lbase = wv * WB + g * (GL + 1);
  const char* xb = (const char*)xg + q * 8;
  float s0 = 0.f, s1 = 0.f, s2 = 0.f, s3 = 0.f;
  float a[4][4];
#pragma unroll
  for (int d = 0; d < 4; d++)
#pragma unroll
    for (int h = 0; h < 4; h++) a[d][h] = 0.f;

  for (int c = e0; c < e1; c += GL) {
    int nc = min(GL, e1 - c);
    float w0 = 0.f, w1 = 0.f, w2 = 0.f, w3 = 0.f;
    int sB = 0;
    if (q < nc) {
      int sidx = esrc2[c + q];
      float4 av = as4[sidx];
      w0 = __expf(lrelu(av.x + ad.x));
      w1 = __expf(lrelu(av.y + ad.y));
      w2 = __expf(lrelu(av.z + ad.z));
      w3 = __expf(lrelu(av.w + ad.w));
      sB = sidx << 7;
    }
    s0 += w0; s1 += w1; s2 += w2; s3 += w3;
    sOff[lbase + q] = sB;
    sW[lbase + q] = make_float4(w0, w1, w2, w3);
    __builtin_amdgcn_wave_barrier();
    for (int i = 0; i < nc; ++i) {
      float4 w = sW[lbase + i];
      uint2 px = *(const uint2*)(xb + sOff[lbase + i]);
      float2 f01 = __half22float2(*(const __half2*)&px.x);
      float2 f23 = __half22float2(*(const __half2*)&px.y);
      a[0][0] = fmaf(w.x, f01.x, a[0][0]); a[0][1] = fmaf(w.y, f01.x, a[0][1]);
      a[0][2] = fmaf(w.z, f01.x, a[0][2]); a[0][3] = fmaf(w.w, f01.x, a[0][3]);
      a[1][0] = fmaf(w.x, f01.y, a[1][0]); a[1][1] = fmaf(w.y, f01.y, a[1][1]);
      a[1][2] = fmaf(w.z, f01.y, a[1][2]); a[1][3] = fmaf(w.w, f01.y, a[1][3]);
      a[2][0] = fmaf(w.x, f23.x, a[2][0]); a[2][1] = fmaf(w.y, f23.x, a[2][1]);
      a[2][2] = fmaf(w.z, f23.x, a[2][2]); a[2][3] = fmaf(w.w, f23.x, a[2][3]);
      a[3][0] = fmaf(w.x, f23.y, a[3][0]); a[3][1] = fmaf(w.y, f23.y, a[3][1]);
      a[3][2] = fmaf(w.z, f23.y, a[3][2]); a[3][3] = fmaf(w.w, f23.y, a[3][3]);
    }
    __builtin_amdgcn_wave_barrier();
  }
#pragma unroll
  for (int off = 1; off < GL; off <<= 1) {
    s0 += __shfl_xor(s0, off);
    s1 += __shfl_xor(s1, off);
    s2 += __shfl_xor(s2, off);
    s3 += __shfl_xor(s3, off);
  }
  float r0 = 1.f / (s0 + 1e-16f), r1 = 1.f / (s1 + 1e-16f);
  float r2 = 1.f / (s2 + 1e-16f), r3 = 1.f / (s3 + 1e-16f);
  __half2 pp[8];
#pragma unroll
  for (int d = 0; d < 4; d++) {
    float sc = scale[q * 4 + d], sh = shift[q * 4 + d];
    pp[2 * d] = __floats2half2_rn(fmaf(a[d][0] * r0, sc, sh), fmaf(a[d][1] * r1, sc, sh));
    pp[2 * d + 1] = __floats2half2_rn(fmaf(a[d][2] * r2, sc, sh), fmaf(a[d][3] * r3, sc, sh));
  }
  uint4 lo = make_uint4(*(unsigned*)&pp[0], *(unsigned*)&pp[1], *(unsigned*)&pp[2], *(unsigned*)&pp[3]);
  uint4 hi = make_uint4(*(unsigned*)&pp[4], *(unsigned*)&pp[5], *(unsigned*)&pp[6], *(unsigned*)&pp[7]);
  *(uint4*)&aT[row * 264 + q * 16] = lo;
  *(uint4*)&aT[row * 264 + q * 16 + 8] = hi;
  __syncthreads();
  if (wv < NCT) {
    int ct = wv;
    int m = lane & 15, kg = lane >> 4;
    f32x4 cacc = (f32x4){0.f, 0.f, 0.f, 0.f};
#pragma unroll
    for (int kt = 0; kt < 8; kt++) {
      half8 avf = *(const half8*)&aT[m * 264 + kt * 32 + kg * 8];
      half8 bvf = *(const half8*)(wfrag + ((kt * NCT + ct) * 64 + lane) * 8);
      cacc = __builtin_amdgcn_mfma_f32_16x16x32_f16(avf, bvf, cacc, 0, 0, 0);
    }
    float bv = bias[ct * 16 + m];
    float psum = 0.f, psq = 0.f;
#pragma unroll
    for (int j = 0; j < 4; j++) {
      int pr = blockIdx.x * 16 + kg * 4 + j;
      float ov = fmaxf(fmaf(cacc[j], 0.25f, bv), 0.f);
      if constexpr (OUTH) {
        out16[(size_t)pr * DOUT + ct * 16 + m] = __float2half(ov);  // coalesced
      } else {
        int nr = perm[pr];  // back to original layout for pooling
        out32[(size_t)nr * DOUT + ct * 16 + m] = ov;
      }
      psum += ov;
      psq = fmaf(ov, ov, psq);
    }
    psum += __shfl_xor(psum, 16); psum += __shfl_xor(psum, 32);
    psq += __shfl_xor(psq, 16); psq += __shfl_xor(psq, 32);
    if (kg == 0) {
      part[(size_t)blockIdx.x * (2 * DOUT) + ct * 16 + m] = psum;
      part[(size_t)blockIdx.x * (2 * DOUT) + DOUT + ct * 16 + m] = psq;
    }
  }
}

// ---------------- BN finalize from per-block partials: grid = C blocks ----------------
template <int C>
__global__ __launch_bounds__(256) void k_bnfin2(const float* __restrict__ part, int nb,
                                                const float* __restrict__ g,
                                                const float* __restrict__ be,
                                                float* __restrict__ scale,
                                                float* __restrict__ shift) {
  int c = blockIdx.x;
  int t = threadIdx.x;
  float s = 0.f, q = 0.f;
  for (int b = t; b < nb; b += 256) {
    s += part[(size_t)b * (2 * C) + c];
    q += part[(size_t)b * (2 * C) + C + c];
  }
  __shared__ float sh[512];
  sh[t] = s;
  sh[256 + t] = q;
  __syncthreads();
  for (int step = 128; step; step >>= 1) {
    if (t < step) {
      sh[t] += sh[t + step];
      sh[256 + t] += sh[256 + t + step];
    }
    __syncthreads();
  }
  if (t == 0) {
    float mean = sh[0] / (float)N_NODES;
    float var = sh[256] / (float)N_NODES - mean * mean;
    float sc = g[c] * rsqrtf(var + 1e-5f);
    scale[c] = sc;
    shift[c] = be[c] - mean * sc;
  }
}

// ---------------- pooling (applies layer-3 BN on load; batch sorted, original layout) ----------------
__global__ __launch_bounds__(256) void k_pool(const float* __restrict__ f3,
                                              const int* __restrict__ batch,
                                              const float* __restrict__ scale,
                                              const float* __restrict__ shift,
                                              float* __restrict__ pool,
                                              float* __restrict__ cntg) {
  __shared__ float acc[NG][33];
  int t = threadIdx.x;
  for (int i = t; i < NG * 33; i += 256) ((float*)acc)[i] = 0.f;
  __syncthreads();
  int c = t & 31, rg = t >> 5;
  float sc = scale[c], sh = shift[c];
  int n0 = blockIdx.x * POOL_NPB;
  int n1 = min(N_NODES, n0 + POOL_NPB);
  float r = 0.f, rc = 0.f;
  int gcur = -1;
  for (int n = n0 + rg; n < n1; n += 8) {
    int g = batch[n];
    if (g != gcur) {
      if (gcur >= 0) {
        atomicAdd(&acc[gcur][c], r);
        if (c == 0) atomicAdd(&acc[gcur][32], rc);
      }
      gcur = g;
      r = 0.f;
      rc = 0.f;
    }
    r += fmaf(f3[(size_t)n * 32 + c], sc, sh);
    rc += 1.f;
  }
  if (gcur >= 0) {
    atomicAdd(&acc[gcur][c], r);
    if (c == 0) atomicAdd(&acc[gcur][32], rc);
  }
  __syncthreads();
  for (int i = t; i < NG * 32; i += 256) {
    int g = i >> 5, cc = i & 31;
    float v = acc[g][cc];
    if (v != 0.f) atomicAdd(&pool[i], v);
  }
  for (int g = t; g < NG; g += 256) {
    float v = acc[g][32];
    if (v != 0.f) atomicAdd(&cntg[g], v);
  }
}

__global__ void k_mlp(const float* __restrict__ pool, const float* __restrict__ cntg,
                      const float* __restrict__ Wp1, const float* __restrict__ bp1,
                      const float* __restrict__ Wp2, const float* __restrict__ bp2,
                      float* __restrict__ out) {
  int g = threadIdx.x;
  if (g >= NG) return;
  float inv = 1.f / fmaxf(cntg[g], 1.f);
  float p[32];
#pragma unroll
  for (int c = 0; c < 32; c++) p[c] = pool[g * 32 + c] * inv;
  float o = bp2[0];
  for (int j = 0; j < 16; j++) {
    float hsum = bp1[j];
#pragma unroll
    for (int c = 0; c < 32; c++) hsum = fmaf(p[c], Wp1[c * 16 + j], hsum);
    o = fmaf(fmaxf(hsum, 0.f), Wp2[j], o);
  }
  out[g] = o;
}

extern "C" void kernel_launch(void* const* d_in, const int* in_sizes, int n_in,
                              void* d_out, int out_size, void* d_ws, size_t ws_size,
                              hipStream_t stream) {
  const float* x = (const float*)d_in[0];
  const int* ei = (const int*)d_in[1];
  const int* batch = (const int*)d_in[2];
  const float* W1 = (const float*)d_in[3];
  const float* aS1 = (const float*)d_in[4];
  const float* aD1 = (const float*)d_in[5];
  const float* b1 = (const float*)d_in[6];
  const float* g1 = (const float*)d_in[7];
  const float* be1 = (const float*)d_in[8];
  const float* W2 = (const float*)d_in[9];
  const float* aS2 = (const float*)d_in[10];
  const float* aD2 = (const float*)d_in[11];
  const float* b2 = (const float*)d_in[12];
  const float* g2 = (const float*)d_in[13];
  const float* be2 = (const float*)d_in[14];
  const float* W3 = (const float*)d_in[15];
  const float* aS3 = (const float*)d_in[16];
  const float* aD3 = (const float*)d_in[17];
  const float* b3 = (const float*)d_in[18];
  const float* g3 = (const float*)d_in[19];
  const float* be3 = (const float*)d_in[20];
  const float* Wp1 = (const float*)d_in[21];
  const float* bp1 = (const float*)d_in[22];
  const float* Wp2 = (const float*)d_in[23];
  const float* bp2 = (const float*)d_in[24];
  float* out = (float*)d_out;

  size_t off = 0;
  auto alloc = [&](size_t bytes) -> void* {
    void* p = (char*)d_ws + off;
    off += (bytes + 255) & ~(size_t)255;
    return p;
  };
  // zeroed region (single memset): pool, cntg, ghist, binCur
  float* pool = (float*)alloc((size_t)NG * 32 * 4);
  float* cntg = (float*)alloc((size_t)NG * 4);
  int* ghist = (int*)alloc((size_t)NBINS * 4);
  int* binCur = (int*)alloc((size_t)NBINS * 4);
  size_t zbytes = off;
  int* gCursor = (int*)alloc((size_t)NBUCK * 4);
  int* bstart = (int*)alloc((size_t)(NBUCK + 1) * 4);
  unsigned int* pairs = (unsigned int*)alloc((size_t)NBUCK * BCAP * 4);
  int* indptr = (int*)alloc((size_t)(N_NODES + 1) * 4);
  int* esrc = (int*)alloc((size_t)EP * 4);
  int* esrc2 = (int*)alloc((size_t)EP * 4);
  int* perm = (int*)alloc((size_t)N_NODES * 4);
  int* pinv = (int*)alloc((size_t)N_NODES * 4);
  int* stp = (int*)alloc((size_t)N_NODES * 4);
  int* enp = (int*)alloc((size_t)N_NODES * 4);
  float* xp = (float*)alloc((size_t)N_NODES * 8 * 4);
  __half* t16a = (__half*)alloc((size_t)N_NODES * 64 * 2);
  __half* t16b = (__half*)alloc((size_t)N_NODES * 64 * 2);
  float* as_ = (float*)alloc((size_t)N_NODES * 16);
  float* ad_ = (float*)alloc((size_t)N_NODES * 16);
  float* tbuf = (float*)alloc((size_t)N_NODES * 32 * 4);
  float* part = (float*)alloc((size_t)NBLK2 * 128 * 4);
  float* scale = (float*)alloc(64 * 4);
  float* shift = (float*)alloc(64 * 4);
  float* wS1 = (float*)alloc(32 * 4);
  float* wD1 = (float*)alloc(32 * 4);
  float* wS2 = (float*)alloc(256 * 4);
  float* wD2 = (float*)alloc(256 * 4);
  float* wS3 = (float*)alloc(256 * 4);
  float* wD3 = (float*)alloc(256 * 4);
  __half* wf1 = (__half*)alloc((size_t)4 * 512 * 2);
  __half* wf2 = (__half*)alloc((size_t)32 * 512 * 2);
  __half* wf3 = (__half*)alloc((size_t)16 * 512 * 2);
  if (off > ws_size) return;

  hipMemsetAsync(pool, 0, zbytes, stream);

  k_prep<<<16 + cdiv(NBUCK, 256), 256, 0, stream>>>(W1, aS1, aD1, W2, aS2, aD2, W3, aS3, aD3,
                                                    wS1, wD1, wS2, wD2, wS3, wD3, wf1, wf2, wf3,
                                                    gCursor);
  k_bucket<<<cdiv(EP, BCHUNK), 256, 0, stream>>>(ei, gCursor, pairs);
  k_bscan<<<1, 1024, 0, stream>>>(gCursor, bstart);
  k_build<<<NBUCK, 256, 0, stream>>>(pairs, bstart, indptr, esrc, ghist);
  k_dscat<<<cdiv(N_NODES, 512), 256, 0, stream>>>(ghist, indptr, binCur, perm, pinv);
  k_etrans<<<cdiv(EP, 256), 256, 0, stream>>>(esrc, pinv, indptr, perm, esrc2, stp, enp);

  // ---- layer 1: permute x + dots; fused gather + MFMA -> t16a (permuted) ----
  k_prex1<<<cdiv(N_NODES, 256), 256, 0, stream>>>(x, perm, wS1, wD1, xp,
                                                  (float4*)as_, (float4*)ad_);
  k_aggp1<<<NBLK1, 256, 0, stream>>>(stp, enp, esrc2, xp, (const float4*)as_,
                                     (const float4*)ad_, wf1, b1, t16a, part);
  k_bnfin2<64><<<64, 256, 0, stream>>>(part, NBLK1, g1, be1, scale, shift);

  // ---- layer 2: dots on t16a (BN1); gather t16a + fold BN1 -> t16b (permuted) ----
  k_dots<<<cdiv(N_NODES, 4), 256, 0, stream>>>(t16a, scale, shift, wS2, wD2,
                                               (float4*)as_, (float4*)ad_);
  k_aggp<64, true><<<NBLK2, 256, 0, stream>>>(stp, enp, esrc2, t16a, (const float4*)as_,
                                              (const float4*)ad_, wf2, b2, scale, shift,
                                              perm, t16b, nullptr, part);
  k_bnfin2<64><<<64, 256, 0, stream>>>(part, NBLK2, g2, be2, scale, shift);

  // ---- layer 3: dots on t16b (BN2); gather t16b + fold BN2 -> tbuf fp32 (original) ----
  k_dots<<<cdiv(N_NODES, 4), 256, 0, stream>>>(t16b, scale, shift, wS3, wD3,
                                               (float4*)as_, (float4*)ad_);
  k_aggp<32, false><<<NBLK2, 256, 0, stream>>>(stp, enp, esrc2, t16b, (const float4*)as_,
                                               (const float4*)ad_, wf3, b3, scale, shift,
                                               perm, nullptr, tbuf, part);
  k_bnfin2<32><<<32, 256, 0, stream>>>(part, NBLK2, g3, be3, scale, shift);

  // ---- pool (BN3 on load) + MLP ----
  k_pool<<<cdiv(N_NODES, POOL_NPB), 256, 0, stream>>>(tbuf, batch, scale, shift, pool, cntg);
  k_mlp<<<1, 64, 0, stream>>>(pool, cntg, Wp1, bp1, Wp2, bp2, out);
}